// Round 15
// baseline (1553.669 us; speedup 1.0000x reference)
//
#include <hip/hip_runtime.h>
#include <hip/hip_cooperative_groups.h>
#include <cstddef>
#include <cstdint>

// MinimalRNNCell h_T: purely linear scan.
//   g_c = sum_{i<8} x_{8c+i} @ (W R^{7-i}) -- ONE MFMA GEMM (x-gather @ stacked G^T)
//   8-level tree combine with Q_l = R^(8*2^l); h0 injected into chunk 0 pre-tree.
// R15: the 12 serial tail launches (measured ~25us fixed cost each) collapse into
// TWO cooperative persistent launches of `stagesk` (512 blocks = 2/CU resident):
// blocks stripe over 128x64 tile-tasks per stage, grid.sync() between stages.
// GEMM body = R13 mk2 verbatim (bit-identical); fallback to per-stage regular
// launches if cooperative launch is rejected. main4 = R14 (300us, verified).
// absmax must remain exactly 1.622593e32.

namespace {

constexpr int BATCH = 32;
constexpr int T = 2048;
constexpr int U = 1024;
constexpr int LJ = 8;
constexpr int CJ = T / LJ;      // 256 chunks
constexpr int MJ = CJ * BATCH;  // 8192 aggregate rows

typedef _Float16 f16;
typedef _Float16 f16x4 __attribute__((ext_vector_type(4)));
typedef _Float16 f16x8 __attribute__((ext_vector_type(8)));
typedef float f32x4 __attribute__((ext_vector_type(4)));

namespace cg = cooperative_groups;

__device__ inline void gload16(const void* g, void* l) {
    __builtin_amdgcn_global_load_lds(
        (const __attribute__((address_space(1))) unsigned int*)g,
        (__attribute__((address_space(3))) unsigned int*)l, 16, 0, 0);
}

// ---------------- x -> f16 (hi only) ----------------
__global__ __launch_bounds__(256)
void split_x(const float* __restrict__ x, f16* __restrict__ xh, long n4)
{
    long i = (long)blockIdx.x * 256 + threadIdx.x;
    const long stride = (long)gridDim.x * 256;
    for (; i < n4; i += stride) {
        const float4 v = *(const float4*)(x + i * 4);
        f16x4 h;
        h.x = (f16)v.x; h.y = (f16)v.y; h.z = (f16)v.z; h.w = (f16)v.w;
        *(f16x4*)(xh + i * 4) = h;
    }
}

// ---------------- prep: T-split + row-split of R and W; row-split h0 ------------
__global__ __launch_bounds__(256)
void prep(const float* __restrict__ R, const float* __restrict__ W,
          const float* __restrict__ h0,
          f16* __restrict__ TTRh, f16* __restrict__ TTRl,
          f16* __restrict__ Rrh, f16* __restrict__ Rrl,
          f16* __restrict__ GhT, f16* __restrict__ GlT,
          f16* __restrict__ Wrh, f16* __restrict__ Wrl,
          f16* __restrict__ h0rh, f16* __restrict__ h0rl)
{
    const int z = blockIdx.z;
    const float* S = z ? W : R;
    f16* Dh = z ? GhT : TTRh;
    f16* Dl = z ? GlT : TTRl;
    const long dstride = z ? 8192 : 1024;
    const long doff = z ? 7168 : 0;
    f16* Rh_ = z ? Wrh : Rrh;
    f16* Rl_ = z ? Wrl : Rrl;

    __shared__ float tile[32][33];
    const int t = threadIdx.x;
    const int k0 = blockIdx.x * 32;
    const int n0 = blockIdx.y * 32;
    {
        const int r = t >> 3, c4 = (t & 7) << 2;
        const float4 v = *(const float4*)(S + (size_t)(k0 + r) * U + n0 + c4);
        tile[r][c4 + 0] = v.x; tile[r][c4 + 1] = v.y;
        tile[r][c4 + 2] = v.z; tile[r][c4 + 3] = v.w;
        f16x4 h, lo;
        h.x = (f16)v.x; lo.x = (f16)((v.x - (float)h.x) * 2048.0f);
        h.y = (f16)v.y; lo.y = (f16)((v.y - (float)h.y) * 2048.0f);
        h.z = (f16)v.z; lo.z = (f16)((v.z - (float)h.z) * 2048.0f);
        h.w = (f16)v.w; lo.w = (f16)((v.w - (float)h.w) * 2048.0f);
        const size_t ro = (size_t)(k0 + r) * U + n0 + c4;
        *(f16x4*)(Rh_ + ro) = h;
        *(f16x4*)(Rl_ + ro) = lo;
    }
    __syncthreads();
    {
        const int c = t >> 3, r4 = (t & 7) << 2;
        float v0 = tile[r4 + 0][c], v1 = tile[r4 + 1][c],
              v2 = tile[r4 + 2][c], v3 = tile[r4 + 3][c];
        f16x4 h, lo;
        h.x = (f16)v0; lo.x = (f16)((v0 - (float)h.x) * 2048.0f);
        h.y = (f16)v1; lo.y = (f16)((v1 - (float)h.y) * 2048.0f);
        h.z = (f16)v2; lo.z = (f16)((v2 - (float)h.z) * 2048.0f);
        h.w = (f16)v3; lo.w = (f16)((v3 - (float)h.w) * 2048.0f);
        const size_t o = (size_t)(n0 + c) * dstride + doff + k0 + r4;
        *(f16x4*)(Dh + o) = h;
        *(f16x4*)(Dl + o) = lo;
    }
    if (z == 1 && blockIdx.x == 0) {
        const int r = t >> 3, c4 = (t & 7) << 2;
        const float4 v = *(const float4*)(h0 + (size_t)r * U + n0 + c4);
        f16x4 h, lo;
        h.x = (f16)v.x; lo.x = (f16)((v.x - (float)h.x) * 2048.0f);
        h.y = (f16)v.y; lo.y = (f16)((v.y - (float)h.y) * 2048.0f);
        h.z = (f16)v.z; lo.z = (f16)((v.z - (float)h.z) * 2048.0f);
        h.w = (f16)v.w; lo.w = (f16)((v.w - (float)h.w) * 2048.0f);
        const size_t ro = (size_t)r * U + n0 + c4;
        *(f16x4*)(h0rh + ro) = h;
        *(f16x4*)(h0rl + ro) = lo;
    }
}

// ---------------- main GEMM (R14: counted-vmcnt 2-deep, 300us verified) ---------
__global__ __launch_bounds__(512, 2)
void main4(const f16* __restrict__ xh, const f16* __restrict__ GhT,
           const f16* __restrict__ GlT, float* __restrict__ g0,
           f16* __restrict__ g0rh, f16* __restrict__ g0rl)
{
    __shared__ __align__(16) f16 LA[2][16384];
    __shared__ __align__(16) f16 LBh[2][8192];
    __shared__ __align__(16) f16 LBl[2][8192];

    const int tid  = threadIdx.x;
    const int lane = tid & 63;
    const int w    = tid >> 6;
    const int wm   = w >> 1;
    const int wn   = w & 1;
    const int r0   = blockIdx.x * 256;
    const int c0   = blockIdx.y * 128;

    const int ch  = tid & 7;
    const int rid = tid >> 3;

    size_t aof[4];
    #pragma unroll
    for (int q = 0; q < 4; ++q) {
        const int m = q * 64 + rid;
        const int arow = r0 + m;
        const size_t xbase = ((size_t)(arow & 31) * T + (size_t)(arow >> 5) * LJ) * U;
        aof[q] = xbase * 2 + (size_t)((ch ^ (m & 7)) << 4);
    }
    size_t bof[2];
    #pragma unroll
    for (int q = 0; q < 2; ++q) {
        const int c = q * 64 + rid;
        bof[q] = ((size_t)(c0 + c) << 14) + (size_t)((ch ^ (c & 7)) << 4);
    }
    const int dst = tid << 4;

    f32x4 hh[4][4], xx[4][4];
    #pragma unroll
    for (int mi = 0; mi < 4; ++mi)
        #pragma unroll
        for (int ni = 0; ni < 4; ++ni) {
            hh[mi][ni] = (f32x4){0.f, 0.f, 0.f, 0.f};
            xx[mi][ni] = (f32x4){0.f, 0.f, 0.f, 0.f};
        }

    auto stage = [&](int b, int kt) {
        const size_t kb = (size_t)kt << 7;
        #pragma unroll
        for (int q = 0; q < 4; ++q)
            gload16((const char*)xh + aof[q] + kb, (char*)&LA[b][0] + q * 8192 + dst);
        #pragma unroll
        for (int q = 0; q < 2; ++q) {
            gload16((const char*)GhT + bof[q] + kb, (char*)&LBh[b][0] + q * 8192 + dst);
            gload16((const char*)GlT + bof[q] + kb, (char*)&LBl[b][0] + q * 8192 + dst);
        }
    };

    stage(0, 0);
    stage(1, 1);

    #pragma unroll 1
    for (int kt = 0; kt < 128; ++kt) {
        if (kt < 127) asm volatile("s_waitcnt vmcnt(8)" ::: "memory");
        else          asm volatile("s_waitcnt vmcnt(0)" ::: "memory");
        __builtin_amdgcn_s_barrier();
        asm volatile("" ::: "memory");

        const int buf = kt & 1;
        #pragma unroll
        for (int ks = 0; ks < 2; ++ks) {
            const int kg = ks * 4 + (lane >> 4);
            f16x8 af[4], bh[4], bl[4];
            #pragma unroll
            for (int mi = 0; mi < 4; ++mi) {
                const int rr = wm * 64 + mi * 16 + (lane & 15);
                const int byte = rr * 128 + ((kg ^ (rr & 7)) << 4);
                af[mi] = *(const f16x8*)((const char*)&LA[buf][0] + byte);
            }
            #pragma unroll
            for (int ni = 0; ni < 4; ++ni) {
                const int cc = wn * 64 + ni * 16 + (lane & 15);
                const int byte = cc * 128 + ((kg ^ (cc & 7)) << 4);
                bh[ni] = *(const f16x8*)((const char*)&LBh[buf][0] + byte);
                bl[ni] = *(const f16x8*)((const char*)&LBl[buf][0] + byte);
            }
            #pragma unroll
            for (int mi = 0; mi < 4; ++mi)
                #pragma unroll
                for (int ni = 0; ni < 4; ++ni) {
                    hh[mi][ni] = __builtin_amdgcn_mfma_f32_16x16x32_f16(af[mi], bh[ni], hh[mi][ni], 0, 0, 0);
                    xx[mi][ni] = __builtin_amdgcn_mfma_f32_16x16x32_f16(af[mi], bl[ni], xx[mi][ni], 0, 0, 0);
                }
        }

        asm volatile("" ::: "memory");
        __builtin_amdgcn_s_barrier();
        asm volatile("" ::: "memory");
        if (kt + 2 < 128) stage(buf, kt + 2);
    }

    #pragma unroll
    for (int mi = 0; mi < 4; ++mi)
        #pragma unroll
        for (int ni = 0; ni < 4; ++ni) {
            const int col = c0 + wn * 64 + ni * 16 + (lane & 15);
            #pragma unroll
            for (int r = 0; r < 4; ++r) {
                const int row = r0 + wm * 64 + mi * 16 + ((lane >> 4) << 2) + r;
                const float val = hh[mi][ni][r] + xx[mi][ni][r] * (1.0f / 2048.0f);
                const size_t o = (size_t)row * U + col;
                g0[o] = val;
                const f16 hv = (f16)val;
                g0rh[o] = hv;
                g0rl[o] = (f16)((val - (float)hv) * 2048.0f);
            }
        }
}

// ---------------- split-GEMM task body (R13 mk2 verbatim, parameterized) --------
struct MDesc {
    const f16* Ah; const f16* Al;
    const f16* BhT; const f16* BlT;
    const float* Aadd;
    float* C;
    f16* EhT; f16* ElT;
    f16* Rh; f16* Rl;
    long estride, eoff;
    int M;
    int amode;      // 0 linear, 2 tree gather
    int cmode;      // 0 store, 1 add (RMW)
    float cscale, escale, fescale;
};

struct TaskStage { MDesc j0, j1; int ny0, ny1; };
struct KArgs { TaskStage st[9]; int nst; };

__device__ void gemm_body(const MDesc& d, int xc, int yr, f16* SMEM)
{
    __syncthreads();   // SMEM reuse guard across tasks within a block
    const int r0 = yr * 128;
    if (r0 >= d.M) return;          // uniform per block-task
    const int c0 = xc * 64;

    f16 (*LAs)[2][4096] = (f16(*)[2][4096])(&SMEM[0]);
    f16 (*LBs)[2][2048] = (f16(*)[2][2048])(&SMEM[16384]);

    const int tid = threadIdx.x;
    const int lane = tid & 63;
    const int w = tid >> 6;
    const int wm = w >> 1, wn = w & 1;

    size_t asrc[2]; int adst[2];
    #pragma unroll
    for (int i = 0; i < 2; ++i) {
        const int c = tid + 256 * i;
        const int prow = c >> 3;
        const int chn = (c & 7) ^ (prow & 7);
        const int row = 2 * prow + (chn >> 2);
        int gr = r0 + row;
        if (gr >= d.M) gr = d.M - 1;
        const int ar = (d.amode == 2) ? (((gr >> 5) << 6) + (gr & 31)) : gr;
        asrc[i] = (size_t)ar * 2048 + (size_t)((chn & 3) << 4);
        adst[i] = c * 16;
    }
    const int bprow = tid >> 3;
    const int bchn = (tid & 7) ^ (bprow & 7);
    const size_t bsrc = (size_t)(c0 + 2 * bprow + (bchn >> 2)) * 2048
                      + (size_t)((bchn & 3) << 4);
    const int bdst = tid * 16;

    f32x4 hh[4][2], xx[4][2];
    #pragma unroll
    for (int mi = 0; mi < 4; ++mi)
        #pragma unroll
        for (int ni = 0; ni < 2; ++ni) {
            hh[mi][ni] = (f32x4){0.f, 0.f, 0.f, 0.f};
            xx[mi][ni] = (f32x4){0.f, 0.f, 0.f, 0.f};
        }

    auto stg = [&](int b, int kt) {
        const size_t kb = (size_t)kt << 6;   // 32 f16 = 64 B
        #pragma unroll
        for (int i = 0; i < 2; ++i) {
            gload16((const char*)d.Ah + asrc[i] + kb, (char*)&LAs[b][0][0] + adst[i]);
            gload16((const char*)d.Al + asrc[i] + kb, (char*)&LAs[b][1][0] + adst[i]);
        }
        gload16((const char*)d.BhT + bsrc + kb, (char*)&LBs[b][0][0] + bdst);
        gload16((const char*)d.BlT + bsrc + kb, (char*)&LBs[b][1][0] + bdst);
    };

    stg(0, 0);
    __syncthreads();

    int buf = 0;
    #pragma unroll 1
    for (int kt = 0; kt < 32; ++kt) {
        if (kt + 1 < 32) stg(buf ^ 1, kt + 1);

        {
            const int kg = lane >> 4;
            f16x8 ah[4], al[4], bh[2], bl[2];
            #pragma unroll
            for (int mi = 0; mi < 4; ++mi) {
                const int rr = wm * 64 + mi * 16 + (lane & 15);
                const int prow = rr >> 1;
                const int chn = 4 * (rr & 1) + kg;
                const int byte = prow * 128 + ((chn ^ (prow & 7)) << 4);
                ah[mi] = *(const f16x8*)((const char*)&LAs[buf][0][0] + byte);
                al[mi] = *(const f16x8*)((const char*)&LAs[buf][1][0] + byte);
            }
            #pragma unroll
            for (int ni = 0; ni < 2; ++ni) {
                const int cc = wn * 32 + ni * 16 + (lane & 15);
                const int prow = cc >> 1;
                const int chn = 4 * (cc & 1) + kg;
                const int byte = prow * 128 + ((chn ^ (prow & 7)) << 4);
                bh[ni] = *(const f16x8*)((const char*)&LBs[buf][0][0] + byte);
                bl[ni] = *(const f16x8*)((const char*)&LBs[buf][1][0] + byte);
            }
            #pragma unroll
            for (int mi = 0; mi < 4; ++mi)
                #pragma unroll
                for (int ni = 0; ni < 2; ++ni) {
                    hh[mi][ni] = __builtin_amdgcn_mfma_f32_16x16x32_f16(ah[mi], bh[ni], hh[mi][ni], 0, 0, 0);
                    xx[mi][ni] = __builtin_amdgcn_mfma_f32_16x16x32_f16(ah[mi], bl[ni], xx[mi][ni], 0, 0, 0);
                    xx[mi][ni] = __builtin_amdgcn_mfma_f32_16x16x32_f16(al[mi], bh[ni], xx[mi][ni], 0, 0, 0);
                }
        }
        __syncthreads();
        buf ^= 1;
    }

    const bool temit = (d.EhT != nullptr);
    f16* Ehs = &SMEM[0];
    f16* Els = &SMEM[8192];

    #pragma unroll
    for (int mi = 0; mi < 4; ++mi) {
        #pragma unroll
        for (int ni = 0; ni < 2; ++ni) {
            const int orow = wm * 64 + mi * 16 + ((lane >> 4) << 2);
            const int colL = wn * 32 + ni * 16 + (lane & 15);
            const int col  = c0 + colL;
            float o[4];
            #pragma unroll
            for (int r = 0; r < 4; ++r) {
                o[r] = (hh[mi][ni][r] + xx[mi][ni][r] * (1.0f / 2048.0f)) * d.cscale;
                const int grow = r0 + orow + r;
                if (grow < d.M) {
                    if (d.amode == 2) {
                        const int arow2 = (((grow >> 5) << 6) + (grow & 31)) + 32;
                        o[r] += d.Aadd[(size_t)arow2 * U + col];
                    }
                    if (d.C) {
                        float* cp = d.C + (size_t)grow * U + col;
                        if (d.cmode == 1) o[r] += *cp;
                        *cp = o[r];
                    }
                    if (d.Rh) {
                        const float e = o[r] * d.fescale;
                        const f16 hv = (f16)e;
                        d.Rh[(size_t)grow * U + col] = hv;
                        d.Rl[(size_t)grow * U + col] = (f16)((e - (float)hv) * 2048.0f);
                    }
                }
            }
            if (temit && (r0 + orow) < d.M) {
                f16x4 h4, l4;
                #pragma unroll
                for (int r = 0; r < 4; ++r) {
                    const float e = o[r] * d.escale;
                    h4[r] = (f16)e;
                    l4[r] = (f16)((e - (float)h4[r]) * 2048.0f);
                }
                const int blk = orow >> 3;
                const int boff = colL * 256 + ((blk ^ (colL & 15)) << 4) + (orow & 7) * 2;
                *(f16x4*)((char*)Ehs + boff) = h4;
                *(f16x4*)((char*)Els + boff) = l4;
            }
        }
    }

    if (temit) {
        __syncthreads();
        const int c  = tid & 63;
        const int b0 = (tid >> 6) * 4;
        const size_t gbase = (size_t)(c0 + c) * d.estride + d.eoff + (size_t)r0;
        #pragma unroll
        for (int i = 0; i < 4; ++i) {
            const int blk = b0 + i;
            const int off = c * 256 + ((blk ^ (c & 15)) << 4);
            *(f16x8*)(d.EhT + gbase + blk * 8) = *(const f16x8*)((char*)Ehs + off);
            *(f16x8*)(d.ElT + gbase + blk * 8) = *(const f16x8*)((char*)Els + off);
        }
    }
}

// ---------------- persistent cooperative multi-stage kernel ---------------------
__global__ __launch_bounds__(256, 2)
void stagesk(KArgs a)
{
    __shared__ __align__(16) f16 SMEM[24576];
    cg::grid_group grid = cg::this_grid();
    for (int s = 0; s < a.nst; ++s) {
        const TaskStage& st = a.st[s];
        const int n0 = 16 * st.ny0;
        const int ntasks = n0 + 16 * st.ny1;
        for (int t = blockIdx.x; t < ntasks; t += gridDim.x) {
            const bool first = (t < n0);
            const MDesc& d = first ? st.j0 : st.j1;
            const int tt = first ? t : t - n0;
            gemm_body(d, tt & 15, tt >> 4, SMEM);
        }
        grid.sync();
    }
}

// fallback: one stage per regular launch (no grid sync)
__global__ __launch_bounds__(256, 2)
void stage1k(TaskStage st)
{
    __shared__ __align__(16) f16 SMEM[24576];
    const int n0 = 16 * st.ny0;
    const int ntasks = n0 + 16 * st.ny1;
    for (int t = blockIdx.x; t < ntasks; t += gridDim.x) {
        const bool first = (t < n0);
        const MDesc& d = first ? st.j0 : st.j1;
        const int tt = first ? t : t - n0;
        gemm_body(d, tt & 15, tt >> 4, SMEM);
    }
}

} // namespace

extern "C" void kernel_launch(void* const* d_in, const int* in_sizes, int n_in,
                              void* d_out, int out_size, void* d_ws, size_t ws_size,
                              hipStream_t stream) {
    const float* x  = (const float*)d_in[0];
    const float* h0 = (const float*)d_in[1];
    const float* W  = (const float*)d_in[2];
    const float* R  = (const float*)d_in[3];
    float* out = (float*)d_out;

    const size_t M1 = (size_t)1024 * 1024;
    float* g0 = (float*)d_ws;            // 8*M1
    float* gA = g0 + 8 * M1;             // 4*M1
    float* gB = gA + 4 * M1;             // 4*M1
    f16* fp = (f16*)(gB + 4 * M1);
    auto take = [&](size_t n) { f16* r = fp; fp += n; return r; };
    f16* xh   = take(64 * M1);
    f16* GhT  = take(8 * M1);
    f16* GlT  = take(8 * M1);
    f16* Tqh[8]; f16* Tql[8];
    for (int l = 0; l < 8; ++l) { Tqh[l] = take(M1); Tql[l] = take(M1); }
    f16* Qrh[7]; f16* Qrl[7];
    for (int l = 0; l < 7; ++l) { Qrh[l] = take(M1); Qrl[l] = take(M1); }
    f16* Gfrh = take(4 * M1); f16* Gfrl = take(4 * M1);
    f16* h0rh = take(32 * 1024); f16* h0rl = take(32 * 1024);
    f16* g0rh = take(8 * M1); f16* g0rl = take(8 * M1);
    f16* gArh = take(4 * M1); f16* gArl = take(4 * M1);
    f16* gBrh = take(4 * M1); f16* gBrl = take(4 * M1);
    // aliases (time-disjoint, R13-verified):
    f16* TTRh = Tqh[3]; f16* TTRl = Tql[3];
    f16* TT1h = Tqh[1]; f16* TT1l = Tql[1];
    f16* TT2h = Tqh[2]; f16* TT2l = Tql[2];
    f16* Rrh  = Qrh[3]; f16* Rrl  = Qrl[3];
    f16* R2rh = Qrh[1]; f16* R2rl = Qrl[1];
    f16* R4rh = Qrh[2]; f16* R4rl = Qrl[2];

    auto MD2 = [](const f16* Ah, const f16* Al, const f16* Bh, const f16* Bl,
                  const float* Aadd, float* C, f16* Eh, f16* El, long eoff, long estride,
                  f16* Rh, f16* Rl, int M, int amode, int cmode,
                  float cs, float es, float fs) {
        MDesc d;
        d.Ah = Ah; d.Al = Al; d.BhT = Bh; d.BlT = Bl; d.Aadd = Aadd; d.C = C;
        d.EhT = Eh; d.ElT = El; d.Rh = Rh; d.Rl = Rl;
        d.estride = estride; d.eoff = eoff; d.M = M; d.amode = amode; d.cmode = cmode;
        d.cscale = cs; d.escale = es; d.fescale = fs;
        return d;
    };
    MDesc dz = MD2(nullptr, nullptr, nullptr, nullptr, nullptr, nullptr,
                   nullptr, nullptr, 0, 1024, nullptr, nullptr, 0, 0, 0, 1.f, 1.f, 1.f);
    auto ST = [](MDesc a, int ya, MDesc b, int yb) {
        TaskStage s; s.j0 = a; s.ny0 = ya; s.j1 = b; s.ny1 = yb; return s;
    };

    // ---- stage tables ----
    KArgs chainA; chainA.nst = 3;
    chainA.st[0] = ST(
        MD2(Rrh, Rrl, TTRh, TTRl, nullptr, nullptr, TT1h, TT1l, 0, 1024,
            R2rh, R2rl, U, 0, 0, 1.f, 1.f, 1.f), 8,                              // R^2
        MD2(Gfrh + 3 * M1, Gfrl + 3 * M1, TTRh, TTRl, nullptr, nullptr,
            GhT, GlT, 6144, 8192, Gfrh + 2 * M1, Gfrl + 2 * M1, U, 0, 0, 1.f, 1.f, 1.f), 8); // WR->seg6
    chainA.st[1] = ST(
        MD2(R2rh, R2rl, TT1h, TT1l, nullptr, nullptr, TT2h, TT2l, 0, 1024,
            R4rh, R4rl, U, 0, 0, 1.f, 1.f, 1.f), 8,                              // R^4
        MD2(Gfrh + 2 * M1, Gfrl + 2 * M1, TT1h, TT1l, nullptr, nullptr,
            GhT, GlT, 4096, 8192, Gfrh, Gfrl, 2 * U, 0, 0, 1.f, 1.f, 1.f), 16);  // segs 4,5
    chainA.st[2] = ST(
        MD2(R4rh, R4rl, TT2h, TT2l, nullptr, nullptr, Tqh[0], Tql[0], 0, 1024,
            Qrh[0], Qrl[0], U, 0, 0, 1.f, 1.f, 1.f), 8,                          // R^8
        MD2(Gfrh, Gfrl, TT2h, TT2l, nullptr, nullptr,
            GhT, GlT, 0, 8192, nullptr, nullptr, 4 * U, 0, 0, 1.f, 1.f, 1.f), 32); // segs 0..3

    KArgs tailA; tailA.nst = 9;
    tailA.st[0] = ST(
        MD2(h0rh, h0rl, Tqh[0], Tql[0], nullptr, g0, nullptr, nullptr, 0, 1024,
            g0rh, g0rl, BATCH, 0, 1, 1.f, 1.f, 1.f), 1,                          // inject (RMW)
        MD2(Qrh[0], Qrl[0], Tqh[0], Tql[0], nullptr, nullptr, Tqh[1], Tql[1], 0, 1024,
            Qrh[1], Qrl[1], U, 0, 0, 1.f, 1.f, 1.f), 8);                         // sq0

    const float aS[9] = {1.f, 1.f, 1.f, 1.f, 1.f,
                         0.015625f, 9.5367431640625e-07f, 7.105427357601002e-15f, 0.f};
    const float cS[8] = {1.f, 1.f, 1.f, 1.f, 1.f,
                         64.f, 68719476736.f, 1.5474250491067253e26f};
    {
        float* gcur = g0; f16* gcrh = g0rh; f16* gcrl = g0rl;
        float* gnxt = gA; f16* gnrh = gArh; f16* gnrl = gArl;
        float* gprv = gB; f16* gprh = gBrh; f16* gprl = gBrl;
        for (int l = 0; l < 8; ++l) {
            const int M = BATCH * ((CJ / 2) >> l);    // 4096 ... 32
            MDesc dc = MD2(gcrh, gcrl, Tqh[l], Tql[l], gcur, (l == 7) ? out : gnxt,
                           nullptr, nullptr, 0, 1024,
                           (l < 7) ? gnrh : nullptr, (l < 7) ? gnrl : nullptr,
                           M, 2, 0, cS[l], 1.f, aS[l + 1]);
            MDesc dq = dz;
            int yq = 0;
            if (l < 6) {
                const int s = l + 1;
                const float fe = (s == 5) ? 5.960464477539063e-08f : 1.f;   // 2^-24
                const float te = (s == 5) ? 1.52587890625e-05f : 1.f;       // 2^-16
                f16* reh = (s + 1 <= 6) ? Qrh[s + 1] : nullptr;
                f16* rel = (s + 1 <= 6) ? Qrl[s + 1] : nullptr;
                dq = MD2(Qrh[s], Qrl[s], Tqh[s], Tql[s], nullptr, nullptr,
                         Tqh[s + 1], Tql[s + 1], 0, 1024, reh, rel, U, 0, 0, 1.f, te, fe);
                yq = 8;
            }
            tailA.st[1 + l] = ST(dc, (M + 127) >> 7, dq, yq);
            float* tf = gprv; gprv = gcur; gcur = gnxt; gnxt = tf;
            f16* th = gprh; f16* tl = gprl;
            gprh = gcrh; gprl = gcrl;
            gcrh = gnrh; gcrl = gnrl;
            gnrh = th;   gnrl = tl;
        }
    }

    // ---- launches ----
    prep<<<dim3(32, 32, 2), 256, 0, stream>>>(R, W, h0, TTRh, TTRl, Rrh, Rrl,
                                              GhT, GlT,
                                              Gfrh + 3 * M1, Gfrl + 3 * M1,
                                              h0rh, h0rl);
    split_x<<<2048, 256, 0, stream>>>(x, xh, (long)BATCH * T * U / 4);

    bool coop_ok = true;
    {
        void* ka[] = { (void*)&chainA };
        hipError_t rc = hipLaunchCooperativeKernel((const void*)&stagesk,
                                                   dim3(512), dim3(256), ka, 0, stream);
        if (rc != hipSuccess) coop_ok = false;
    }
    if (!coop_ok) {
        for (int s = 0; s < chainA.nst; ++s)
            stage1k<<<dim3(512), 256, 0, stream>>>(chainA.st[s]);
    }

    main4<<<dim3(32, 8), 512, 0, stream>>>(xh, GhT, GlT, g0, g0rh, g0rl);

    if (coop_ok) {
        void* ka[] = { (void*)&tailA };
        hipError_t rc = hipLaunchCooperativeKernel((const void*)&stagesk,
                                                   dim3(512), dim3(256), ka, 0, stream);
        if (rc != hipSuccess) coop_ok = false;
        if (!coop_ok)
            for (int s = 0; s < tailA.nst; ++s)
                stage1k<<<dim3(512), 256, 0, stream>>>(tailA.st[s]);
    } else {
        for (int s = 0; s < tailA.nst; ++s)
            stage1k<<<dim3(512), 256, 0, stream>>>(tailA.st[s]);
    }
    (void)in_sizes; (void)n_in; (void)out_size; (void)ws_size;
}

// Round 16
// 803.060 us; speedup vs baseline: 1.9347x; 1.9347x over previous
//
#include <hip/hip_runtime.h>
#include <cstddef>
#include <cstdint>

// MinimalRNNCell h_T: purely linear scan.
//   g_c = sum_{i<8} x_{8c+i} @ (W R^{7-i}) -- ONE MFMA GEMM (x-gather @ stacked G^T)
//   8-level tree combine with Q_l = R^(8*2^l); h0 injected into chunk 0 pre-tree.
// R16 = R13 structure (802us proven; R15's grid.sync cost ~90us/sync -> reverted)
// with two keepers:
//  - main4: R14 counted-vmcnt 2-deep (300us verified)
//  - mk2: BK 32->64 (per-kt MFMA 120->240cyc, barriers 32->16) + counted
//    vmcnt(12) 2-deep => load latency fully covered. LDS 96KB (1 block/CU --
//    fine, tail stages are latency-bound small grids). Same k-ascending
//    accumulation => absmax must remain exactly 1.622593e32.

namespace {

constexpr int BATCH = 32;
constexpr int T = 2048;
constexpr int U = 1024;
constexpr int LJ = 8;
constexpr int CJ = T / LJ;      // 256 chunks
constexpr int MJ = CJ * BATCH;  // 8192 aggregate rows

typedef _Float16 f16;
typedef _Float16 f16x4 __attribute__((ext_vector_type(4)));
typedef _Float16 f16x8 __attribute__((ext_vector_type(8)));
typedef float f32x4 __attribute__((ext_vector_type(4)));

__device__ inline void gload16(const void* g, void* l) {
    __builtin_amdgcn_global_load_lds(
        (const __attribute__((address_space(1))) unsigned int*)g,
        (__attribute__((address_space(3))) unsigned int*)l, 16, 0, 0);
}

// ---------------- x -> f16 (hi only) ----------------
__global__ __launch_bounds__(256)
void split_x(const float* __restrict__ x, f16* __restrict__ xh, long n4)
{
    long i = (long)blockIdx.x * 256 + threadIdx.x;
    const long stride = (long)gridDim.x * 256;
    for (; i < n4; i += stride) {
        const float4 v = *(const float4*)(x + i * 4);
        f16x4 h;
        h.x = (f16)v.x; h.y = (f16)v.y; h.z = (f16)v.z; h.w = (f16)v.w;
        *(f16x4*)(xh + i * 4) = h;
    }
}

// ---------------- prep: T-split + row-split of R and W; row-split h0 ------------
__global__ __launch_bounds__(256)
void prep(const float* __restrict__ R, const float* __restrict__ W,
          const float* __restrict__ h0,
          f16* __restrict__ TTRh, f16* __restrict__ TTRl,
          f16* __restrict__ Rrh, f16* __restrict__ Rrl,
          f16* __restrict__ GhT, f16* __restrict__ GlT,
          f16* __restrict__ Wrh, f16* __restrict__ Wrl,
          f16* __restrict__ h0rh, f16* __restrict__ h0rl)
{
    const int z = blockIdx.z;
    const float* S = z ? W : R;
    f16* Dh = z ? GhT : TTRh;
    f16* Dl = z ? GlT : TTRl;
    const long dstride = z ? 8192 : 1024;
    const long doff = z ? 7168 : 0;
    f16* Rh_ = z ? Wrh : Rrh;
    f16* Rl_ = z ? Wrl : Rrl;

    __shared__ float tile[32][33];
    const int t = threadIdx.x;
    const int k0 = blockIdx.x * 32;
    const int n0 = blockIdx.y * 32;
    {
        const int r = t >> 3, c4 = (t & 7) << 2;
        const float4 v = *(const float4*)(S + (size_t)(k0 + r) * U + n0 + c4);
        tile[r][c4 + 0] = v.x; tile[r][c4 + 1] = v.y;
        tile[r][c4 + 2] = v.z; tile[r][c4 + 3] = v.w;
        f16x4 h, lo;
        h.x = (f16)v.x; lo.x = (f16)((v.x - (float)h.x) * 2048.0f);
        h.y = (f16)v.y; lo.y = (f16)((v.y - (float)h.y) * 2048.0f);
        h.z = (f16)v.z; lo.z = (f16)((v.z - (float)h.z) * 2048.0f);
        h.w = (f16)v.w; lo.w = (f16)((v.w - (float)h.w) * 2048.0f);
        const size_t ro = (size_t)(k0 + r) * U + n0 + c4;
        *(f16x4*)(Rh_ + ro) = h;
        *(f16x4*)(Rl_ + ro) = lo;
    }
    __syncthreads();
    {
        const int c = t >> 3, r4 = (t & 7) << 2;
        float v0 = tile[r4 + 0][c], v1 = tile[r4 + 1][c],
              v2 = tile[r4 + 2][c], v3 = tile[r4 + 3][c];
        f16x4 h, lo;
        h.x = (f16)v0; lo.x = (f16)((v0 - (float)h.x) * 2048.0f);
        h.y = (f16)v1; lo.y = (f16)((v1 - (float)h.y) * 2048.0f);
        h.z = (f16)v2; lo.z = (f16)((v2 - (float)h.z) * 2048.0f);
        h.w = (f16)v3; lo.w = (f16)((v3 - (float)h.w) * 2048.0f);
        const size_t o = (size_t)(n0 + c) * dstride + doff + k0 + r4;
        *(f16x4*)(Dh + o) = h;
        *(f16x4*)(Dl + o) = lo;
    }
    if (z == 1 && blockIdx.x == 0) {
        const int r = t >> 3, c4 = (t & 7) << 2;
        const float4 v = *(const float4*)(h0 + (size_t)r * U + n0 + c4);
        f16x4 h, lo;
        h.x = (f16)v.x; lo.x = (f16)((v.x - (float)h.x) * 2048.0f);
        h.y = (f16)v.y; lo.y = (f16)((v.y - (float)h.y) * 2048.0f);
        h.z = (f16)v.z; lo.z = (f16)((v.z - (float)h.z) * 2048.0f);
        h.w = (f16)v.w; lo.w = (f16)((v.w - (float)h.w) * 2048.0f);
        const size_t ro = (size_t)r * U + n0 + c4;
        *(f16x4*)(h0rh + ro) = h;
        *(f16x4*)(h0rl + ro) = lo;
    }
}

// ---------------- main GEMM (R14: counted-vmcnt 2-deep, 300us verified) ---------
__global__ __launch_bounds__(512, 2)
void main4(const f16* __restrict__ xh, const f16* __restrict__ GhT,
           const f16* __restrict__ GlT, float* __restrict__ g0,
           f16* __restrict__ g0rh, f16* __restrict__ g0rl)
{
    __shared__ __align__(16) f16 LA[2][16384];
    __shared__ __align__(16) f16 LBh[2][8192];
    __shared__ __align__(16) f16 LBl[2][8192];

    const int tid  = threadIdx.x;
    const int lane = tid & 63;
    const int w    = tid >> 6;
    const int wm   = w >> 1;
    const int wn   = w & 1;
    const int r0   = blockIdx.x * 256;
    const int c0   = blockIdx.y * 128;

    const int ch  = tid & 7;
    const int rid = tid >> 3;

    size_t aof[4];
    #pragma unroll
    for (int q = 0; q < 4; ++q) {
        const int m = q * 64 + rid;
        const int arow = r0 + m;
        const size_t xbase = ((size_t)(arow & 31) * T + (size_t)(arow >> 5) * LJ) * U;
        aof[q] = xbase * 2 + (size_t)((ch ^ (m & 7)) << 4);
    }
    size_t bof[2];
    #pragma unroll
    for (int q = 0; q < 2; ++q) {
        const int c = q * 64 + rid;
        bof[q] = ((size_t)(c0 + c) << 14) + (size_t)((ch ^ (c & 7)) << 4);
    }
    const int dst = tid << 4;

    f32x4 hh[4][4], xx[4][4];
    #pragma unroll
    for (int mi = 0; mi < 4; ++mi)
        #pragma unroll
        for (int ni = 0; ni < 4; ++ni) {
            hh[mi][ni] = (f32x4){0.f, 0.f, 0.f, 0.f};
            xx[mi][ni] = (f32x4){0.f, 0.f, 0.f, 0.f};
        }

    auto stage = [&](int b, int kt) {
        const size_t kb = (size_t)kt << 7;
        #pragma unroll
        for (int q = 0; q < 4; ++q)
            gload16((const char*)xh + aof[q] + kb, (char*)&LA[b][0] + q * 8192 + dst);
        #pragma unroll
        for (int q = 0; q < 2; ++q) {
            gload16((const char*)GhT + bof[q] + kb, (char*)&LBh[b][0] + q * 8192 + dst);
            gload16((const char*)GlT + bof[q] + kb, (char*)&LBl[b][0] + q * 8192 + dst);
        }
    };

    stage(0, 0);
    stage(1, 1);

    #pragma unroll 1
    for (int kt = 0; kt < 128; ++kt) {
        if (kt < 127) asm volatile("s_waitcnt vmcnt(8)" ::: "memory");
        else          asm volatile("s_waitcnt vmcnt(0)" ::: "memory");
        __builtin_amdgcn_s_barrier();
        asm volatile("" ::: "memory");

        const int buf = kt & 1;
        #pragma unroll
        for (int ks = 0; ks < 2; ++ks) {
            const int kg = ks * 4 + (lane >> 4);
            f16x8 af[4], bh[4], bl[4];
            #pragma unroll
            for (int mi = 0; mi < 4; ++mi) {
                const int rr = wm * 64 + mi * 16 + (lane & 15);
                const int byte = rr * 128 + ((kg ^ (rr & 7)) << 4);
                af[mi] = *(const f16x8*)((const char*)&LA[buf][0] + byte);
            }
            #pragma unroll
            for (int ni = 0; ni < 4; ++ni) {
                const int cc = wn * 64 + ni * 16 + (lane & 15);
                const int byte = cc * 128 + ((kg ^ (cc & 7)) << 4);
                bh[ni] = *(const f16x8*)((const char*)&LBh[buf][0] + byte);
                bl[ni] = *(const f16x8*)((const char*)&LBl[buf][0] + byte);
            }
            #pragma unroll
            for (int mi = 0; mi < 4; ++mi)
                #pragma unroll
                for (int ni = 0; ni < 4; ++ni) {
                    hh[mi][ni] = __builtin_amdgcn_mfma_f32_16x16x32_f16(af[mi], bh[ni], hh[mi][ni], 0, 0, 0);
                    xx[mi][ni] = __builtin_amdgcn_mfma_f32_16x16x32_f16(af[mi], bl[ni], xx[mi][ni], 0, 0, 0);
                }
        }

        asm volatile("" ::: "memory");
        __builtin_amdgcn_s_barrier();
        asm volatile("" ::: "memory");
        if (kt + 2 < 128) stage(buf, kt + 2);
    }

    #pragma unroll
    for (int mi = 0; mi < 4; ++mi)
        #pragma unroll
        for (int ni = 0; ni < 4; ++ni) {
            const int col = c0 + wn * 64 + ni * 16 + (lane & 15);
            #pragma unroll
            for (int r = 0; r < 4; ++r) {
                const int row = r0 + wm * 64 + mi * 16 + ((lane >> 4) << 2) + r;
                const float val = hh[mi][ni][r] + xx[mi][ni][r] * (1.0f / 2048.0f);
                const size_t o = (size_t)row * U + col;
                g0[o] = val;
                const f16 hv = (f16)val;
                g0rh[o] = hv;
                g0rl[o] = (f16)((val - (float)hv) * 2048.0f);
            }
        }
}

// ---------------- mk2: all-async split-GEMM, BK=64, counted-vmcnt 2-deep --------
// 128x64 tile, A/B in main4's linear-dest + (chunk ^ (row&7)) swizzle layout.
struct MDesc {
    const f16* Ah; const f16* Al;     // row-major [M][1024] pair
    const f16* BhT; const f16* BlT;   // col-major [1024][1024] pair
    const float* Aadd;                // fp32 for amode2 epilogue add
    float* C;                         // fp32 out (or null)
    f16* EhT; f16* ElT;               // transposed emit (or null)
    f16* Rh; f16* Rl;                 // row-split emit (or null)
    long estride, eoff;
    int M;
    int amode;      // 0 linear, 2 tree gather
    int cmode;      // 0 store, 1 add (RMW)
    float cscale, escale, fescale;
};

__global__ __launch_bounds__(256, 1)
void mk2(MDesc d0, MDesc d1)
{
    MDesc d = blockIdx.z ? d1 : d0;
    const int r0 = blockIdx.y * 128;
    if (r0 >= d.M) return;
    const int c0 = blockIdx.x * 64;

    __shared__ __align__(16) f16 SMEM[49152];                // 96 KB
    f16 (*LAs)[2][8192] = (f16(*)[2][8192])(&SMEM[0]);       // [buf][h/l] 16 KB each
    f16 (*LBs)[2][4096] = (f16(*)[2][4096])(&SMEM[32768]);   // [buf][h/l] 8 KB each

    const int tid = threadIdx.x;
    const int lane = tid & 63;
    const int w = tid >> 6;
    const int wm = w >> 1, wn = w & 1;   // wave = 64 rows x 32 cols

    // A staging: 4 chunks/thread per h/l (128 rows x 8 chunks of 16B)
    size_t asrc[4]; int adst[4];
    #pragma unroll
    for (int i = 0; i < 4; ++i) {
        const int c = tid + 256 * i;        // 0..1023
        const int prow = c >> 3;            // row 0..127
        const int chn = (c & 7) ^ (prow & 7);
        int gr = r0 + prow;
        if (gr >= d.M) gr = d.M - 1;
        const int ar = (d.amode == 2) ? (((gr >> 5) << 6) + (gr & 31)) : gr;
        asrc[i] = (size_t)ar * 2048 + (size_t)(chn << 4);
        adst[i] = c * 16;
    }
    // B staging: 2 chunks/thread per h/l (64 cols x 8 chunks)
    size_t bsrc[2]; int bdst[2];
    #pragma unroll
    for (int i = 0; i < 2; ++i) {
        const int c = tid + 256 * i;        // 0..511
        const int prow = c >> 3;            // col 0..63
        const int chn = (c & 7) ^ (prow & 7);
        bsrc[i] = (size_t)(c0 + prow) * 2048 + (size_t)(chn << 4);
        bdst[i] = c * 16;
    }

    f32x4 hh[4][2], xx[4][2];
    #pragma unroll
    for (int mi = 0; mi < 4; ++mi)
        #pragma unroll
        for (int ni = 0; ni < 2; ++ni) {
            hh[mi][ni] = (f32x4){0.f, 0.f, 0.f, 0.f};
            xx[mi][ni] = (f32x4){0.f, 0.f, 0.f, 0.f};
        }

    auto stg = [&](int b, int kt) {
        const size_t kb = (size_t)kt << 7;   // 64 f16 = 128 B
        #pragma unroll
        for (int i = 0; i < 4; ++i) {
            gload16((const char*)d.Ah + asrc[i] + kb, (char*)&LAs[b][0][0] + adst[i]);
            gload16((const char*)d.Al + asrc[i] + kb, (char*)&LAs[b][1][0] + adst[i]);
        }
        #pragma unroll
        for (int i = 0; i < 2; ++i) {
            gload16((const char*)d.BhT + bsrc[i] + kb, (char*)&LBs[b][0][0] + bdst[i]);
            gload16((const char*)d.BlT + bsrc[i] + kb, (char*)&LBs[b][1][0] + bdst[i]);
        }
    };

    stg(0, 0);
    stg(1, 1);          // 24 loads in flight (12 per stage)

    #pragma unroll 1
    for (int kt = 0; kt < 16; ++kt) {
        if (kt < 15) asm volatile("s_waitcnt vmcnt(12)" ::: "memory");
        else         asm volatile("s_waitcnt vmcnt(0)" ::: "memory");
        __builtin_amdgcn_s_barrier();
        asm volatile("" ::: "memory");

        const int buf = kt & 1;
        #pragma unroll
        for (int ks = 0; ks < 2; ++ks) {
            const int kg = ks * 4 + (lane >> 4);
            f16x8 ah[4], al[4], bh[2], bl[2];
            #pragma unroll
            for (int mi = 0; mi < 4; ++mi) {
                const int rr = wm * 64 + mi * 16 + (lane & 15);
                const int byte = rr * 128 + ((kg ^ (rr & 7)) << 4);
                ah[mi] = *(const f16x8*)((const char*)&LAs[buf][0][0] + byte);
                al[mi] = *(const f16x8*)((const char*)&LAs[buf][1][0] + byte);
            }
            #pragma unroll
            for (int ni = 0; ni < 2; ++ni) {
                const int cc = wn * 32 + ni * 16 + (lane & 15);
                const int byte = cc * 128 + ((kg ^ (cc & 7)) << 4);
                bh[ni] = *(const f16x8*)((const char*)&LBs[buf][0][0] + byte);
                bl[ni] = *(const f16x8*)((const char*)&LBs[buf][1][0] + byte);
            }
            #pragma unroll
            for (int mi = 0; mi < 4; ++mi)
                #pragma unroll
                for (int ni = 0; ni < 2; ++ni) {
                    hh[mi][ni] = __builtin_amdgcn_mfma_f32_16x16x32_f16(ah[mi], bh[ni], hh[mi][ni], 0, 0, 0);
                    xx[mi][ni] = __builtin_amdgcn_mfma_f32_16x16x32_f16(ah[mi], bl[ni], xx[mi][ni], 0, 0, 0);
                    xx[mi][ni] = __builtin_amdgcn_mfma_f32_16x16x32_f16(al[mi], bh[ni], xx[mi][ni], 0, 0, 0);
                }
        }

        asm volatile("" ::: "memory");
        __builtin_amdgcn_s_barrier();
        asm volatile("" ::: "memory");
        if (kt + 2 < 16) stg(buf, kt + 2);
    }

    // ---- epilogue ----
    const bool temit = (d.EhT != nullptr);
    f16* Ehs = &SMEM[0];       // [64 col][128 row] swizzled, 16 KB each
    f16* Els = &SMEM[8192];

    #pragma unroll
    for (int mi = 0; mi < 4; ++mi) {
        #pragma unroll
        for (int ni = 0; ni < 2; ++ni) {
            const int orow = wm * 64 + mi * 16 + ((lane >> 4) << 2);
            const int colL = wn * 32 + ni * 16 + (lane & 15);
            const int col  = c0 + colL;
            float o[4];
            #pragma unroll
            for (int r = 0; r < 4; ++r) {
                o[r] = (hh[mi][ni][r] + xx[mi][ni][r] * (1.0f / 2048.0f)) * d.cscale;
                const int grow = r0 + orow + r;
                if (grow < d.M) {
                    if (d.amode == 2) {
                        const int arow2 = (((grow >> 5) << 6) + (grow & 31)) + 32;
                        o[r] += d.Aadd[(size_t)arow2 * U + col];
                    }
                    if (d.C) {
                        float* cp = d.C + (size_t)grow * U + col;
                        if (d.cmode == 1) o[r] += *cp;
                        *cp = o[r];
                    }
                    if (d.Rh) {
                        const float e = o[r] * d.fescale;
                        const f16 hv = (f16)e;
                        d.Rh[(size_t)grow * U + col] = hv;
                        d.Rl[(size_t)grow * U + col] = (f16)((e - (float)hv) * 2048.0f);
                    }
                }
            }
            if (temit && (r0 + orow) < d.M) {
                f16x4 h4, l4;
                #pragma unroll
                for (int r = 0; r < 4; ++r) {
                    const float e = o[r] * d.escale;
                    h4[r] = (f16)e;
                    l4[r] = (f16)((e - (float)h4[r]) * 2048.0f);
                }
                const int blk = orow >> 3;
                const int boff = colL * 256 + ((blk ^ (colL & 15)) << 4) + (orow & 7) * 2;
                *(f16x4*)((char*)Ehs + boff) = h4;
                *(f16x4*)((char*)Els + boff) = l4;
            }
        }
    }

    if (temit) {
        __syncthreads();
        const int c  = tid & 63;
        const int b0 = (tid >> 6) * 4;
        const size_t gbase = (size_t)(c0 + c) * d.estride + d.eoff + (size_t)r0;
        #pragma unroll
        for (int i = 0; i < 4; ++i) {
            const int blk = b0 + i;
            const int off = c * 256 + ((blk ^ (c & 15)) << 4);
            *(f16x8*)(d.EhT + gbase + blk * 8) = *(const f16x8*)((char*)Ehs + off);
            *(f16x8*)(d.ElT + gbase + blk * 8) = *(const f16x8*)((char*)Els + off);
        }
    }
}

} // namespace

extern "C" void kernel_launch(void* const* d_in, const int* in_sizes, int n_in,
                              void* d_out, int out_size, void* d_ws, size_t ws_size,
                              hipStream_t stream) {
    const float* x  = (const float*)d_in[0];
    const float* h0 = (const float*)d_in[1];
    const float* W  = (const float*)d_in[2];
    const float* R  = (const float*)d_in[3];
    float* out = (float*)d_out;

    const size_t M1 = (size_t)1024 * 1024;
    float* g0 = (float*)d_ws;            // 8*M1
    float* gA = g0 + 8 * M1;             // 4*M1
    float* gB = gA + 4 * M1;             // 4*M1
    f16* fp = (f16*)(gB + 4 * M1);
    auto take = [&](size_t n) { f16* r = fp; fp += n; return r; };
    f16* xh   = take(64 * M1);
    f16* GhT  = take(8 * M1);
    f16* GlT  = take(8 * M1);
    f16* Tqh[8]; f16* Tql[8];
    for (int l = 0; l < 8; ++l) { Tqh[l] = take(M1); Tql[l] = take(M1); }
    f16* Qrh[7]; f16* Qrl[7];
    for (int l = 0; l < 7; ++l) { Qrh[l] = take(M1); Qrl[l] = take(M1); }
    f16* Gfrh = take(4 * M1); f16* Gfrl = take(4 * M1);
    f16* h0rh = take(32 * 1024); f16* h0rl = take(32 * 1024);
    f16* g0rh = take(8 * M1); f16* g0rl = take(8 * M1);
    f16* gArh = take(4 * M1); f16* gArl = take(4 * M1);
    f16* gBrh = take(4 * M1); f16* gBrl = take(4 * M1);
    // aliases (time-disjoint, R13-verified):
    f16* TTRh = Tqh[3]; f16* TTRl = Tql[3];
    f16* TT1h = Tqh[1]; f16* TT1l = Tql[1];
    f16* TT2h = Tqh[2]; f16* TT2l = Tql[2];
    f16* Rrh  = Qrh[3]; f16* Rrl  = Qrl[3];
    f16* R2rh = Qrh[1]; f16* R2rl = Qrl[1];
    f16* R4rh = Qrh[2]; f16* R4rl = Qrl[2];

    auto MD2 = [](const f16* Ah, const f16* Al, const f16* Bh, const f16* Bl,
                  const float* Aadd, float* C, f16* Eh, f16* El, long eoff, long estride,
                  f16* Rh, f16* Rl, int M, int amode, int cmode,
                  float cs, float es, float fs) {
        MDesc d;
        d.Ah = Ah; d.Al = Al; d.BhT = Bh; d.BlT = Bl; d.Aadd = Aadd; d.C = C;
        d.EhT = Eh; d.ElT = El; d.Rh = Rh; d.Rl = Rl;
        d.estride = estride; d.eoff = eoff; d.M = M; d.amode = amode; d.cmode = cmode;
        d.cscale = cs; d.escale = es; d.fescale = fs;
        return d;
    };
    MDesc dz = MD2(nullptr, nullptr, nullptr, nullptr, nullptr, nullptr,
                   nullptr, nullptr, 0, 1024, nullptr, nullptr, 0, 0, 0, 1.f, 1.f, 1.f);
    auto PAIR = [&](MDesc a, MDesc b) {
        int y0 = (a.M + 127) >> 7, y1 = (b.M + 127) >> 7;
        int y = y0 > y1 ? y0 : y1; if (y < 1) y = 1;
        mk2<<<dim3(16, (unsigned)y, 2), 256, 0, stream>>>(a, b);
    };

    // 0) conversions
    prep<<<dim3(32, 32, 2), 256, 0, stream>>>(R, W, h0, TTRh, TTRl, Rrh, Rrl,
                                              GhT, GlT,
                                              Gfrh + 3 * M1, Gfrl + 3 * M1,
                                              h0rh, h0rl);
    split_x<<<2048, 256, 0, stream>>>(x, xh, (long)BATCH * T * U / 4);

    // 1) G-build + R-power chain, 3 fused launches
    PAIR(MD2(Rrh, Rrl, TTRh, TTRl, nullptr, nullptr, TT1h, TT1l, 0, 1024,
             R2rh, R2rl, U, 0, 0, 1.f, 1.f, 1.f),                               // R^2
         MD2(Gfrh + 3 * M1, Gfrl + 3 * M1, TTRh, TTRl, nullptr, nullptr,
             GhT, GlT, 6144, 8192, Gfrh + 2 * M1, Gfrl + 2 * M1, U, 0, 0, 1.f, 1.f, 1.f)); // WR -> seg6
    PAIR(MD2(R2rh, R2rl, TT1h, TT1l, nullptr, nullptr, TT2h, TT2l, 0, 1024,
             R4rh, R4rl, U, 0, 0, 1.f, 1.f, 1.f),                               // R^4
         MD2(Gfrh + 2 * M1, Gfrl + 2 * M1, TT1h, TT1l, nullptr, nullptr,
             GhT, GlT, 4096, 8192, Gfrh, Gfrl, 2 * U, 0, 0, 1.f, 1.f, 1.f));    // segs 4,5
    PAIR(MD2(R4rh, R4rl, TT2h, TT2l, nullptr, nullptr, Tqh[0], Tql[0], 0, 1024,
             Qrh[0], Qrl[0], U, 0, 0, 1.f, 1.f, 1.f),                           // R^8
         MD2(Gfrh, Gfrl, TT2h, TT2l, nullptr, nullptr,
             GhT, GlT, 0, 8192, nullptr, nullptr, 4 * U, 0, 0, 1.f, 1.f, 1.f)); // segs 0..3

    // 2) main GEMM (emits g0 row-split)
    main4<<<dim3(32, 8), 512, 0, stream>>>(xh, GhT, GlT, g0, g0rh, g0rl);

    // 3) inject (g0[0:32] += h0 @ R^8, RMW + re-emit) || squaring0
    PAIR(MD2(h0rh, h0rl, Tqh[0], Tql[0], nullptr, g0, nullptr, nullptr, 0, 1024,
             g0rh, g0rl, BATCH, 0, 1, 1.f, 1.f, 1.f),
         MD2(Qrh[0], Qrl[0], Tqh[0], Tql[0], nullptr, nullptr, Tqh[1], Tql[1], 0, 1024,
             Qrh[1], Qrl[1], U, 0, 0, 1.f, 1.f, 1.f));

    // 4) tree: 8 levels; combine l || squaring l+1
    const float aS[9] = {1.f, 1.f, 1.f, 1.f, 1.f,
                         0.015625f, 9.5367431640625e-07f, 7.105427357601002e-15f, 0.f};
    const float cS[8] = {1.f, 1.f, 1.f, 1.f, 1.f,
                         64.f, 68719476736.f, 1.5474250491067253e26f};
    float* gcur = g0; f16* gcrh = g0rh; f16* gcrl = g0rl;
    float* gnxt = gA; f16* gnrh = gArh; f16* gnrl = gArl;
    float* gprv = gB; f16* gprh = gBrh; f16* gprl = gBrl;
    for (int l = 0; l < 8; ++l) {
        const int M = BATCH * ((CJ / 2) >> l);    // 4096 ... 32
        MDesc dc = MD2(gcrh, gcrl, Tqh[l], Tql[l], gcur, (l == 7) ? out : gnxt,
                       nullptr, nullptr, 0, 1024,
                       (l < 7) ? gnrh : nullptr, (l < 7) ? gnrl : nullptr,
                       M, 2, 0, cS[l], 1.f, aS[l + 1]);
        MDesc dq = dz;
        if (l < 6) {
            const int s = l + 1;
            const float fe = (s == 5) ? 5.960464477539063e-08f : 1.f;   // 2^-24
            const float te = (s == 5) ? 1.52587890625e-05f : 1.f;       // 2^-16
            f16* reh = (s + 1 <= 6) ? Qrh[s + 1] : nullptr;
            f16* rel = (s + 1 <= 6) ? Qrl[s + 1] : nullptr;
            dq = MD2(Qrh[s], Qrl[s], Tqh[s], Tql[s], nullptr, nullptr,
                     Tqh[s + 1], Tql[s + 1], 0, 1024, reh, rel, U, 0, 0, 1.f, te, fe);
        }
        PAIR(dc, dq);
        float* tf = gprv; gprv = gcur; gcur = gnxt; gnxt = tf;
        f16* th = gprh; f16* tl = gprl;
        gprh = gcrh; gprl = gcrl;
        gcrh = gnrh; gcrl = gnrl;
        gnrh = th;   gnrl = tl;
    }
    (void)in_sizes; (void)n_in; (void)out_size; (void)ws_size;
}

// Round 17
// 774.140 us; speedup vs baseline: 2.0070x; 1.0374x over previous
//
#include <hip/hip_runtime.h>
#include <cstddef>
#include <cstdint>

// MinimalRNNCell h_T: purely linear scan.
//   g_c = sum_{i<8} x_{8c+i} @ (W R^{7-i}) -- ONE MFMA GEMM (x-gather @ stacked G^T)
//   8-level tree combine with Q_l = R^(8*2^l); h0 injected into chunk 0 pre-tree.
// R17 = R16 with ONE change: main4 drops G's lo-term (B = Gh only, single
// accumulator). Rationale: R7 proved dropping x's lo-term was invisible in absmax
// (bit-identical 1.622593e32) -- G = W*R^(<=7) has no dangerous compounding (the
// tree's Q-powers keep full 2-term splits), so G-lo is the same error class
// (~2^-11 relative, passed linearly). Halves main-GEMM MFMA work.
// Predicted absmax 1.5-3.5e32 (vs threshold 6.75e32); revert if > 4e32.

namespace {

constexpr int BATCH = 32;
constexpr int T = 2048;
constexpr int U = 1024;
constexpr int LJ = 8;
constexpr int CJ = T / LJ;      // 256 chunks
constexpr int MJ = CJ * BATCH;  // 8192 aggregate rows

typedef _Float16 f16;
typedef _Float16 f16x4 __attribute__((ext_vector_type(4)));
typedef _Float16 f16x8 __attribute__((ext_vector_type(8)));
typedef float f32x4 __attribute__((ext_vector_type(4)));

__device__ inline void gload16(const void* g, void* l) {
    __builtin_amdgcn_global_load_lds(
        (const __attribute__((address_space(1))) unsigned int*)g,
        (__attribute__((address_space(3))) unsigned int*)l, 16, 0, 0);
}

// ---------------- x -> f16 (hi only) ----------------
__global__ __launch_bounds__(256)
void split_x(const float* __restrict__ x, f16* __restrict__ xh, long n4)
{
    long i = (long)blockIdx.x * 256 + threadIdx.x;
    const long stride = (long)gridDim.x * 256;
    for (; i < n4; i += stride) {
        const float4 v = *(const float4*)(x + i * 4);
        f16x4 h;
        h.x = (f16)v.x; h.y = (f16)v.y; h.z = (f16)v.z; h.w = (f16)v.w;
        *(f16x4*)(xh + i * 4) = h;
    }
}

// ---------------- prep: T-split + row-split of R and W; row-split h0 ------------
__global__ __launch_bounds__(256)
void prep(const float* __restrict__ R, const float* __restrict__ W,
          const float* __restrict__ h0,
          f16* __restrict__ TTRh, f16* __restrict__ TTRl,
          f16* __restrict__ Rrh, f16* __restrict__ Rrl,
          f16* __restrict__ GhT, f16* __restrict__ GlT,
          f16* __restrict__ Wrh, f16* __restrict__ Wrl,
          f16* __restrict__ h0rh, f16* __restrict__ h0rl)
{
    const int z = blockIdx.z;
    const float* S = z ? W : R;
    f16* Dh = z ? GhT : TTRh;
    f16* Dl = z ? GlT : TTRl;
    const long dstride = z ? 8192 : 1024;
    const long doff = z ? 7168 : 0;
    f16* Rh_ = z ? Wrh : Rrh;
    f16* Rl_ = z ? Wrl : Rrl;

    __shared__ float tile[32][33];
    const int t = threadIdx.x;
    const int k0 = blockIdx.x * 32;
    const int n0 = blockIdx.y * 32;
    {
        const int r = t >> 3, c4 = (t & 7) << 2;
        const float4 v = *(const float4*)(S + (size_t)(k0 + r) * U + n0 + c4);
        tile[r][c4 + 0] = v.x; tile[r][c4 + 1] = v.y;
        tile[r][c4 + 2] = v.z; tile[r][c4 + 3] = v.w;
        f16x4 h, lo;
        h.x = (f16)v.x; lo.x = (f16)((v.x - (float)h.x) * 2048.0f);
        h.y = (f16)v.y; lo.y = (f16)((v.y - (float)h.y) * 2048.0f);
        h.z = (f16)v.z; lo.z = (f16)((v.z - (float)h.z) * 2048.0f);
        h.w = (f16)v.w; lo.w = (f16)((v.w - (float)h.w) * 2048.0f);
        const size_t ro = (size_t)(k0 + r) * U + n0 + c4;
        *(f16x4*)(Rh_ + ro) = h;
        *(f16x4*)(Rl_ + ro) = lo;
    }
    __syncthreads();
    {
        const int c = t >> 3, r4 = (t & 7) << 2;
        float v0 = tile[r4 + 0][c], v1 = tile[r4 + 1][c],
              v2 = tile[r4 + 2][c], v3 = tile[r4 + 3][c];
        f16x4 h, lo;
        h.x = (f16)v0; lo.x = (f16)((v0 - (float)h.x) * 2048.0f);
        h.y = (f16)v1; lo.y = (f16)((v1 - (float)h.y) * 2048.0f);
        h.z = (f16)v2; lo.z = (f16)((v2 - (float)h.z) * 2048.0f);
        h.w = (f16)v3; lo.w = (f16)((v3 - (float)h.w) * 2048.0f);
        const size_t o = (size_t)(n0 + c) * dstride + doff + k0 + r4;
        *(f16x4*)(Dh + o) = h;
        *(f16x4*)(Dl + o) = lo;
    }
    if (z == 1 && blockIdx.x == 0) {
        const int r = t >> 3, c4 = (t & 7) << 2;
        const float4 v = *(const float4*)(h0 + (size_t)r * U + n0 + c4);
        f16x4 h, lo;
        h.x = (f16)v.x; lo.x = (f16)((v.x - (float)h.x) * 2048.0f);
        h.y = (f16)v.y; lo.y = (f16)((v.y - (float)h.y) * 2048.0f);
        h.z = (f16)v.z; lo.z = (f16)((v.z - (float)h.z) * 2048.0f);
        h.w = (f16)v.w; lo.w = (f16)((v.w - (float)h.w) * 2048.0f);
        const size_t ro = (size_t)r * U + n0 + c4;
        *(f16x4*)(h0rh + ro) = h;
        *(f16x4*)(h0rl + ro) = lo;
    }
}

// ---------------- main GEMM: g0 = xh-gather @ Gh (hi-only, single acc) ----------
__global__ __launch_bounds__(512, 2)
void main4(const f16* __restrict__ xh, const f16* __restrict__ GhT,
           float* __restrict__ g0, f16* __restrict__ g0rh, f16* __restrict__ g0rl)
{
    __shared__ __align__(16) f16 LA[2][16384];   // 32 KB / buf
    __shared__ __align__(16) f16 LBh[2][8192];   // 16 KB / buf  (96 KB total)

    const int tid  = threadIdx.x;
    const int lane = tid & 63;
    const int w    = tid >> 6;
    const int wm   = w >> 1;
    const int wn   = w & 1;
    const int r0   = blockIdx.x * 256;
    const int c0   = blockIdx.y * 128;

    const int ch  = tid & 7;
    const int rid = tid >> 3;

    size_t aof[4];
    #pragma unroll
    for (int q = 0; q < 4; ++q) {
        const int m = q * 64 + rid;
        const int arow = r0 + m;
        const size_t xbase = ((size_t)(arow & 31) * T + (size_t)(arow >> 5) * LJ) * U;
        aof[q] = xbase * 2 + (size_t)((ch ^ (m & 7)) << 4);
    }
    size_t bof[2];
    #pragma unroll
    for (int q = 0; q < 2; ++q) {
        const int c = q * 64 + rid;
        bof[q] = ((size_t)(c0 + c) << 14) + (size_t)((ch ^ (c & 7)) << 4);
    }
    const int dst = tid << 4;

    f32x4 hh[4][4];
    #pragma unroll
    for (int mi = 0; mi < 4; ++mi)
        #pragma unroll
        for (int ni = 0; ni < 4; ++ni)
            hh[mi][ni] = (f32x4){0.f, 0.f, 0.f, 0.f};

    auto stage = [&](int b, int kt) {
        const size_t kb = (size_t)kt << 7;
        #pragma unroll
        for (int q = 0; q < 4; ++q)
            gload16((const char*)xh + aof[q] + kb, (char*)&LA[b][0] + q * 8192 + dst);
        #pragma unroll
        for (int q = 0; q < 2; ++q)
            gload16((const char*)GhT + bof[q] + kb, (char*)&LBh[b][0] + q * 8192 + dst);
    };

    stage(0, 0);
    stage(1, 1);    // 12 loads in flight per thread

    #pragma unroll 1
    for (int kt = 0; kt < 128; ++kt) {
        if (kt < 127) asm volatile("s_waitcnt vmcnt(6)" ::: "memory");
        else          asm volatile("s_waitcnt vmcnt(0)" ::: "memory");
        __builtin_amdgcn_s_barrier();
        asm volatile("" ::: "memory");

        const int buf = kt & 1;
        #pragma unroll
        for (int ks = 0; ks < 2; ++ks) {
            const int kg = ks * 4 + (lane >> 4);
            f16x8 af[4], bh[4];
            #pragma unroll
            for (int mi = 0; mi < 4; ++mi) {
                const int rr = wm * 64 + mi * 16 + (lane & 15);
                const int byte = rr * 128 + ((kg ^ (rr & 7)) << 4);
                af[mi] = *(const f16x8*)((const char*)&LA[buf][0] + byte);
            }
            #pragma unroll
            for (int ni = 0; ni < 4; ++ni) {
                const int cc = wn * 64 + ni * 16 + (lane & 15);
                const int byte = cc * 128 + ((kg ^ (cc & 7)) << 4);
                bh[ni] = *(const f16x8*)((const char*)&LBh[buf][0] + byte);
            }
            #pragma unroll
            for (int mi = 0; mi < 4; ++mi)
                #pragma unroll
                for (int ni = 0; ni < 4; ++ni)
                    hh[mi][ni] = __builtin_amdgcn_mfma_f32_16x16x32_f16(af[mi], bh[ni], hh[mi][ni], 0, 0, 0);
        }

        asm volatile("" ::: "memory");
        __builtin_amdgcn_s_barrier();
        asm volatile("" ::: "memory");
        if (kt + 2 < 128) stage(buf, kt + 2);
    }

    #pragma unroll
    for (int mi = 0; mi < 4; ++mi)
        #pragma unroll
        for (int ni = 0; ni < 4; ++ni) {
            const int col = c0 + wn * 64 + ni * 16 + (lane & 15);
            #pragma unroll
            for (int r = 0; r < 4; ++r) {
                const int row = r0 + wm * 64 + mi * 16 + ((lane >> 4) << 2) + r;
                const float val = hh[mi][ni][r];
                const size_t o = (size_t)row * U + col;
                g0[o] = val;
                const f16 hv = (f16)val;
                g0rh[o] = hv;
                g0rl[o] = (f16)((val - (float)hv) * 2048.0f);
            }
        }
}

// ---------------- mk2: all-async split-GEMM, BK=64, counted-vmcnt 2-deep --------
struct MDesc {
    const f16* Ah; const f16* Al;     // row-major [M][1024] pair
    const f16* BhT; const f16* BlT;   // col-major [1024][1024] pair
    const float* Aadd;                // fp32 for amode2 epilogue add
    float* C;                         // fp32 out (or null)
    f16* EhT; f16* ElT;               // transposed emit (or null)
    f16* Rh; f16* Rl;                 // row-split emit (or null)
    long estride, eoff;
    int M;
    int amode;      // 0 linear, 2 tree gather
    int cmode;      // 0 store, 1 add (RMW)
    float cscale, escale, fescale;
};

__global__ __launch_bounds__(256, 1)
void mk2(MDesc d0, MDesc d1)
{
    MDesc d = blockIdx.z ? d1 : d0;
    const int r0 = blockIdx.y * 128;
    if (r0 >= d.M) return;
    const int c0 = blockIdx.x * 64;

    __shared__ __align__(16) f16 SMEM[49152];                // 96 KB
    f16 (*LAs)[2][8192] = (f16(*)[2][8192])(&SMEM[0]);
    f16 (*LBs)[2][4096] = (f16(*)[2][4096])(&SMEM[32768]);

    const int tid = threadIdx.x;
    const int lane = tid & 63;
    const int w = tid >> 6;
    const int wm = w >> 1, wn = w & 1;

    size_t asrc[4]; int adst[4];
    #pragma unroll
    for (int i = 0; i < 4; ++i) {
        const int c = tid + 256 * i;
        const int prow = c >> 3;
        const int chn = (c & 7) ^ (prow & 7);
        int gr = r0 + prow;
        if (gr >= d.M) gr = d.M - 1;
        const int ar = (d.amode == 2) ? (((gr >> 5) << 6) + (gr & 31)) : gr;
        asrc[i] = (size_t)ar * 2048 + (size_t)(chn << 4);
        adst[i] = c * 16;
    }
    size_t bsrc[2]; int bdst[2];
    #pragma unroll
    for (int i = 0; i < 2; ++i) {
        const int c = tid + 256 * i;
        const int prow = c >> 3;
        const int chn = (c & 7) ^ (prow & 7);
        bsrc[i] = (size_t)(c0 + prow) * 2048 + (size_t)(chn << 4);
        bdst[i] = c * 16;
    }

    f32x4 hh[4][2], xx[4][2];
    #pragma unroll
    for (int mi = 0; mi < 4; ++mi)
        #pragma unroll
        for (int ni = 0; ni < 2; ++ni) {
            hh[mi][ni] = (f32x4){0.f, 0.f, 0.f, 0.f};
            xx[mi][ni] = (f32x4){0.f, 0.f, 0.f, 0.f};
        }

    auto stg = [&](int b, int kt) {
        const size_t kb = (size_t)kt << 7;   // 64 f16 = 128 B
        #pragma unroll
        for (int i = 0; i < 4; ++i) {
            gload16((const char*)d.Ah + asrc[i] + kb, (char*)&LAs[b][0][0] + adst[i]);
            gload16((const char*)d.Al + asrc[i] + kb, (char*)&LAs[b][1][0] + adst[i]);
        }
        #pragma unroll
        for (int i = 0; i < 2; ++i) {
            gload16((const char*)d.BhT + bsrc[i] + kb, (char*)&LBs[b][0][0] + bdst[i]);
            gload16((const char*)d.BlT + bsrc[i] + kb, (char*)&LBs[b][1][0] + bdst[i]);
        }
    };

    stg(0, 0);
    stg(1, 1);

    #pragma unroll 1
    for (int kt = 0; kt < 16; ++kt) {
        if (kt < 15) asm volatile("s_waitcnt vmcnt(12)" ::: "memory");
        else         asm volatile("s_waitcnt vmcnt(0)" ::: "memory");
        __builtin_amdgcn_s_barrier();
        asm volatile("" ::: "memory");

        const int buf = kt & 1;
        #pragma unroll
        for (int ks = 0; ks < 2; ++ks) {
            const int kg = ks * 4 + (lane >> 4);
            f16x8 ah[4], al[4], bh[2], bl[2];
            #pragma unroll
            for (int mi = 0; mi < 4; ++mi) {
                const int rr = wm * 64 + mi * 16 + (lane & 15);
                const int byte = rr * 128 + ((kg ^ (rr & 7)) << 4);
                ah[mi] = *(const f16x8*)((const char*)&LAs[buf][0][0] + byte);
                al[mi] = *(const f16x8*)((const char*)&LAs[buf][1][0] + byte);
            }
            #pragma unroll
            for (int ni = 0; ni < 2; ++ni) {
                const int cc = wn * 32 + ni * 16 + (lane & 15);
                const int byte = cc * 128 + ((kg ^ (cc & 7)) << 4);
                bh[ni] = *(const f16x8*)((const char*)&LBs[buf][0][0] + byte);
                bl[ni] = *(const f16x8*)((const char*)&LBs[buf][1][0] + byte);
            }
            #pragma unroll
            for (int mi = 0; mi < 4; ++mi)
                #pragma unroll
                for (int ni = 0; ni < 2; ++ni) {
                    hh[mi][ni] = __builtin_amdgcn_mfma_f32_16x16x32_f16(ah[mi], bh[ni], hh[mi][ni], 0, 0, 0);
                    xx[mi][ni] = __builtin_amdgcn_mfma_f32_16x16x32_f16(ah[mi], bl[ni], xx[mi][ni], 0, 0, 0);
                    xx[mi][ni] = __builtin_amdgcn_mfma_f32_16x16x32_f16(al[mi], bh[ni], xx[mi][ni], 0, 0, 0);
                }
        }

        asm volatile("" ::: "memory");
        __builtin_amdgcn_s_barrier();
        asm volatile("" ::: "memory");
        if (kt + 2 < 16) stg(buf, kt + 2);
    }

    // ---- epilogue ----
    const bool temit = (d.EhT != nullptr);
    f16* Ehs = &SMEM[0];
    f16* Els = &SMEM[8192];

    #pragma unroll
    for (int mi = 0; mi < 4; ++mi) {
        #pragma unroll
        for (int ni = 0; ni < 2; ++ni) {
            const int orow = wm * 64 + mi * 16 + ((lane >> 4) << 2);
            const int colL = wn * 32 + ni * 16 + (lane & 15);
            const int col  = c0 + colL;
            float o[4];
            #pragma unroll
            for (int r = 0; r < 4; ++r) {
                o[r] = (hh[mi][ni][r] + xx[mi][ni][r] * (1.0f / 2048.0f)) * d.cscale;
                const int grow = r0 + orow + r;
                if (grow < d.M) {
                    if (d.amode == 2) {
                        const int arow2 = (((grow >> 5) << 6) + (grow & 31)) + 32;
                        o[r] += d.Aadd[(size_t)grow >= 0 ? (size_t)arow2 * U + col : 0];
                    }
                    if (d.C) {
                        float* cp = d.C + (size_t)grow * U + col;
                        if (d.cmode == 1) o[r] += *cp;
                        *cp = o[r];
                    }
                    if (d.Rh) {
                        const float e = o[r] * d.fescale;
                        const f16 hv = (f16)e;
                        d.Rh[(size_t)grow * U + col] = hv;
                        d.Rl[(size_t)grow * U + col] = (f16)((e - (float)hv) * 2048.0f);
                    }
                }
            }
            if (temit && (r0 + orow) < d.M) {
                f16x4 h4, l4;
                #pragma unroll
                for (int r = 0; r < 4; ++r) {
                    const float e = o[r] * d.escale;
                    h4[r] = (f16)e;
                    l4[r] = (f16)((e - (float)h4[r]) * 2048.0f);
                }
                const int blk = orow >> 3;
                const int boff = colL * 256 + ((blk ^ (colL & 15)) << 4) + (orow & 7) * 2;
                *(f16x4*)((char*)Ehs + boff) = h4;
                *(f16x4*)((char*)Els + boff) = l4;
            }
        }
    }

    if (temit) {
        __syncthreads();
        const int c  = tid & 63;
        const int b0 = (tid >> 6) * 4;
        const size_t gbase = (size_t)(c0 + c) * d.estride + d.eoff + (size_t)r0;
        #pragma unroll
        for (int i = 0; i < 4; ++i) {
            const int blk = b0 + i;
            const int off = c * 256 + ((blk ^ (c & 15)) << 4);
            *(f16x8*)(d.EhT + gbase + blk * 8) = *(const f16x8*)((char*)Ehs + off);
            *(f16x8*)(d.ElT + gbase + blk * 8) = *(const f16x8*)((char*)Els + off);
        }
    }
}

} // namespace

extern "C" void kernel_launch(void* const* d_in, const int* in_sizes, int n_in,
                              void* d_out, int out_size, void* d_ws, size_t ws_size,
                              hipStream_t stream) {
    const float* x  = (const float*)d_in[0];
    const float* h0 = (const float*)d_in[1];
    const float* W  = (const float*)d_in[2];
    const float* R  = (const float*)d_in[3];
    float* out = (float*)d_out;

    const size_t M1 = (size_t)1024 * 1024;
    float* g0 = (float*)d_ws;            // 8*M1
    float* gA = g0 + 8 * M1;             // 4*M1
    float* gB = gA + 4 * M1;             // 4*M1
    f16* fp = (f16*)(gB + 4 * M1);
    auto take = [&](size_t n) { f16* r = fp; fp += n; return r; };
    f16* xh   = take(64 * M1);
    f16* GhT  = take(8 * M1);
    f16* GlT  = take(8 * M1);
    f16* Tqh[8]; f16* Tql[8];
    for (int l = 0; l < 8; ++l) { Tqh[l] = take(M1); Tql[l] = take(M1); }
    f16* Qrh[7]; f16* Qrl[7];
    for (int l = 0; l < 7; ++l) { Qrh[l] = take(M1); Qrl[l] = take(M1); }
    f16* Gfrh = take(4 * M1); f16* Gfrl = take(4 * M1);
    f16* h0rh = take(32 * 1024); f16* h0rl = take(32 * 1024);
    f16* g0rh = take(8 * M1); f16* g0rl = take(8 * M1);
    f16* gArh = take(4 * M1); f16* gArl = take(4 * M1);
    f16* gBrh = take(4 * M1); f16* gBrl = take(4 * M1);
    // aliases (time-disjoint, R13-verified):
    f16* TTRh = Tqh[3]; f16* TTRl = Tql[3];
    f16* TT1h = Tqh[1]; f16* TT1l = Tql[1];
    f16* TT2h = Tqh[2]; f16* TT2l = Tql[2];
    f16* Rrh  = Qrh[3]; f16* Rrl  = Qrl[3];
    f16* R2rh = Qrh[1]; f16* R2rl = Qrl[1];
    f16* R4rh = Qrh[2]; f16* R4rl = Qrl[2];

    auto MD2 = [](const f16* Ah, const f16* Al, const f16* Bh, const f16* Bl,
                  const float* Aadd, float* C, f16* Eh, f16* El, long eoff, long estride,
                  f16* Rh, f16* Rl, int M, int amode, int cmode,
                  float cs, float es, float fs) {
        MDesc d;
        d.Ah = Ah; d.Al = Al; d.BhT = Bh; d.BlT = Bl; d.Aadd = Aadd; d.C = C;
        d.EhT = Eh; d.ElT = El; d.Rh = Rh; d.Rl = Rl;
        d.estride = estride; d.eoff = eoff; d.M = M; d.amode = amode; d.cmode = cmode;
        d.cscale = cs; d.escale = es; d.fescale = fs;
        return d;
    };
    MDesc dz = MD2(nullptr, nullptr, nullptr, nullptr, nullptr, nullptr,
                   nullptr, nullptr, 0, 1024, nullptr, nullptr, 0, 0, 0, 1.f, 1.f, 1.f);
    auto PAIR = [&](MDesc a, MDesc b) {
        int y0 = (a.M + 127) >> 7, y1 = (b.M + 127) >> 7;
        int y = y0 > y1 ? y0 : y1; if (y < 1) y = 1;
        mk2<<<dim3(16, (unsigned)y, 2), 256, 0, stream>>>(a, b);
    };

    // 0) conversions
    prep<<<dim3(32, 32, 2), 256, 0, stream>>>(R, W, h0, TTRh, TTRl, Rrh, Rrl,
                                              GhT, GlT,
                                              Gfrh + 3 * M1, Gfrl + 3 * M1,
                                              h0rh, h0rl);
    split_x<<<2048, 256, 0, stream>>>(x, xh, (long)BATCH * T * U / 4);

    // 1) G-build + R-power chain, 3 fused launches
    PAIR(MD2(Rrh, Rrl, TTRh, TTRl, nullptr, nullptr, TT1h, TT1l, 0, 1024,
             R2rh, R2rl, U, 0, 0, 1.f, 1.f, 1.f),                               // R^2
         MD2(Gfrh + 3 * M1, Gfrl + 3 * M1, TTRh, TTRl, nullptr, nullptr,
             GhT, GlT, 6144, 8192, Gfrh + 2 * M1, Gfrl + 2 * M1, U, 0, 0, 1.f, 1.f, 1.f)); // WR -> seg6
    PAIR(MD2(R2rh, R2rl, TT1h, TT1l, nullptr, nullptr, TT2h, TT2l, 0, 1024,
             R4rh, R4rl, U, 0, 0, 1.f, 1.f, 1.f),                               // R^4
         MD2(Gfrh + 2 * M1, Gfrl + 2 * M1, TT1h, TT1l, nullptr, nullptr,
             GhT, GlT, 4096, 8192, Gfrh, Gfrl, 2 * U, 0, 0, 1.f, 1.f, 1.f));    // segs 4,5
    PAIR(MD2(R4rh, R4rl, TT2h, TT2l, nullptr, nullptr, Tqh[0], Tql[0], 0, 1024,
             Qrh[0], Qrl[0], U, 0, 0, 1.f, 1.f, 1.f),                           // R^8
         MD2(Gfrh, Gfrl, TT2h, TT2l, nullptr, nullptr,
             GhT, GlT, 0, 8192, nullptr, nullptr, 4 * U, 0, 0, 1.f, 1.f, 1.f)); // segs 0..3

    // 2) main GEMM (hi-only B; emits g0 row-split)
    main4<<<dim3(32, 8), 512, 0, stream>>>(xh, GhT, g0, g0rh, g0rl);

    // 3) inject (g0[0:32] += h0 @ R^8, RMW + re-emit) || squaring0
    PAIR(MD2(h0rh, h0rl, Tqh[0], Tql[0], nullptr, g0, nullptr, nullptr, 0, 1024,
             g0rh, g0rl, BATCH, 0, 1, 1.f, 1.f, 1.f),
         MD2(Qrh[0], Qrl[0], Tqh[0], Tql[0], nullptr, nullptr, Tqh[1], Tql[1], 0, 1024,
             Qrh[1], Qrl[1], U, 0, 0, 1.f, 1.f, 1.f));

    // 4) tree: 8 levels; combine l || squaring l+1
    const float aS[9] = {1.f, 1.f, 1.f, 1.f, 1.f,
                         0.015625f, 9.5367431640625e-07f, 7.105427357601002e-15f, 0.f};
    const float cS[8] = {1.f, 1.f, 1.f, 1.f, 1.f,
                         64.f, 68719476736.f, 1.5474250491067253e26f};
    float* gcur = g0; f16* gcrh = g0rh; f16* gcrl = g0rl;
    float* gnxt = gA; f16* gnrh = gArh; f16* gnrl = gArl;
    float* gprv = gB; f16* gprh = gBrh; f16* gprl = gBrl;
    for (int l = 0; l < 8; ++l) {
        const int M = BATCH * ((CJ / 2) >> l);    // 4096 ... 32
        MDesc dc = MD2(gcrh, gcrl, Tqh[l], Tql[l], gcur, (l == 7) ? out : gnxt,
                       nullptr, nullptr, 0, 1024,
                       (l < 7) ? gnrh : nullptr, (l < 7) ? gnrl : nullptr,
                       M, 2, 0, cS[l], 1.f, aS[l + 1]);
        MDesc dq = dz;
        if (l < 6) {
            const int s = l + 1;
            const float fe = (s == 5) ? 5.960464477539063e-08f : 1.f;   // 2^-24
            const float te = (s == 5) ? 1.52587890625e-05f : 1.f;       // 2^-16
            f16* reh = (s + 1 <= 6) ? Qrh[s + 1] : nullptr;
            f16* rel = (s + 1 <= 6) ? Qrl[s + 1] : nullptr;
            dq = MD2(Qrh[s], Qrl[s], Tqh[s], Tql[s], nullptr, nullptr,
                     Tqh[s + 1], Tql[s + 1], 0, 1024, reh, rel, U, 0, 0, 1.f, te, fe);
        }
        PAIR(dc, dq);
        float* tf = gprv; gprv = gcur; gcur = gnxt; gnxt = tf;
        f16* th = gprh; f16* tl = gprl;
        gprh = gcrh; gprl = gcrl;
        gcrh = gnrh; gcrl = gnrl;
        gnrh = th;   gnrl = tl;
    }
    (void)in_sizes; (void)n_in; (void)out_size; (void)ws_size;
}

// Round 18
// 692.676 us; speedup vs baseline: 2.2430x; 1.1176x over previous
//
#include <hip/hip_runtime.h>
#include <cstddef>
#include <cstdint>

// MinimalRNNCell h_T: purely linear scan.
//   g_c = sum_{i<8} x_{8c+i} @ (W R^{7-i}) -- ONE MFMA GEMM (x-gather @ stacked G^T)
//   8-level tree combine with Q_l = R^(8*2^l); h0 injected into chunk 0 pre-tree.
// R18 = R17 with main GEMM rebuilt for TLP: main5 = 128x128 tile, 256 thr
// (4 waves), 64KB dbuf LDS -> 2 blocks/CU (R17's 96KB/1-block had 94% stall:
// 5100 cyc/kt vs 310 cyc MFMA -- no second block to cover HBM latency).
// Grid (64 row, 8 col): same-row col-blocks are 64 apart = 0 mod 8 -> same XCD
// (L2-shared A panels, R8-proven). Same k-ascending accumulation order =>
// absmax must remain exactly 1.622593e32.

namespace {

constexpr int BATCH = 32;
constexpr int T = 2048;
constexpr int U = 1024;
constexpr int LJ = 8;
constexpr int CJ = T / LJ;      // 256 chunks
constexpr int MJ = CJ * BATCH;  // 8192 aggregate rows

typedef _Float16 f16;
typedef _Float16 f16x4 __attribute__((ext_vector_type(4)));
typedef _Float16 f16x8 __attribute__((ext_vector_type(8)));
typedef float f32x4 __attribute__((ext_vector_type(4)));

__device__ inline void gload16(const void* g, void* l) {
    __builtin_amdgcn_global_load_lds(
        (const __attribute__((address_space(1))) unsigned int*)g,
        (__attribute__((address_space(3))) unsigned int*)l, 16, 0, 0);
}

// ---------------- x -> f16 (hi only) ----------------
__global__ __launch_bounds__(256)
void split_x(const float* __restrict__ x, f16* __restrict__ xh, long n4)
{
    long i = (long)blockIdx.x * 256 + threadIdx.x;
    const long stride = (long)gridDim.x * 256;
    for (; i < n4; i += stride) {
        const float4 v = *(const float4*)(x + i * 4);
        f16x4 h;
        h.x = (f16)v.x; h.y = (f16)v.y; h.z = (f16)v.z; h.w = (f16)v.w;
        *(f16x4*)(xh + i * 4) = h;
    }
}

// ---------------- prep: T-split + row-split of R and W; row-split h0 ------------
__global__ __launch_bounds__(256)
void prep(const float* __restrict__ R, const float* __restrict__ W,
          const float* __restrict__ h0,
          f16* __restrict__ TTRh, f16* __restrict__ TTRl,
          f16* __restrict__ Rrh, f16* __restrict__ Rrl,
          f16* __restrict__ GhT, f16* __restrict__ GlT,
          f16* __restrict__ Wrh, f16* __restrict__ Wrl,
          f16* __restrict__ h0rh, f16* __restrict__ h0rl)
{
    const int z = blockIdx.z;
    const float* S = z ? W : R;
    f16* Dh = z ? GhT : TTRh;
    f16* Dl = z ? GlT : TTRl;
    const long dstride = z ? 8192 : 1024;
    const long doff = z ? 7168 : 0;
    f16* Rh_ = z ? Wrh : Rrh;
    f16* Rl_ = z ? Wrl : Rrl;

    __shared__ float tile[32][33];
    const int t = threadIdx.x;
    const int k0 = blockIdx.x * 32;
    const int n0 = blockIdx.y * 32;
    {
        const int r = t >> 3, c4 = (t & 7) << 2;
        const float4 v = *(const float4*)(S + (size_t)(k0 + r) * U + n0 + c4);
        tile[r][c4 + 0] = v.x; tile[r][c4 + 1] = v.y;
        tile[r][c4 + 2] = v.z; tile[r][c4 + 3] = v.w;
        f16x4 h, lo;
        h.x = (f16)v.x; lo.x = (f16)((v.x - (float)h.x) * 2048.0f);
        h.y = (f16)v.y; lo.y = (f16)((v.y - (float)h.y) * 2048.0f);
        h.z = (f16)v.z; lo.z = (f16)((v.z - (float)h.z) * 2048.0f);
        h.w = (f16)v.w; lo.w = (f16)((v.w - (float)h.w) * 2048.0f);
        const size_t ro = (size_t)(k0 + r) * U + n0 + c4;
        *(f16x4*)(Rh_ + ro) = h;
        *(f16x4*)(Rl_ + ro) = lo;
    }
    __syncthreads();
    {
        const int c = t >> 3, r4 = (t & 7) << 2;
        float v0 = tile[r4 + 0][c], v1 = tile[r4 + 1][c],
              v2 = tile[r4 + 2][c], v3 = tile[r4 + 3][c];
        f16x4 h, lo;
        h.x = (f16)v0; lo.x = (f16)((v0 - (float)h.x) * 2048.0f);
        h.y = (f16)v1; lo.y = (f16)((v1 - (float)h.y) * 2048.0f);
        h.z = (f16)v2; lo.z = (f16)((v2 - (float)h.z) * 2048.0f);
        h.w = (f16)v3; lo.w = (f16)((v3 - (float)h.w) * 2048.0f);
        const size_t o = (size_t)(n0 + c) * dstride + doff + k0 + r4;
        *(f16x4*)(Dh + o) = h;
        *(f16x4*)(Dl + o) = lo;
    }
    if (z == 1 && blockIdx.x == 0) {
        const int r = t >> 3, c4 = (t & 7) << 2;
        const float4 v = *(const float4*)(h0 + (size_t)r * U + n0 + c4);
        f16x4 h, lo;
        h.x = (f16)v.x; lo.x = (f16)((v.x - (float)h.x) * 2048.0f);
        h.y = (f16)v.y; lo.y = (f16)((v.y - (float)h.y) * 2048.0f);
        h.z = (f16)v.z; lo.z = (f16)((v.z - (float)h.z) * 2048.0f);
        h.w = (f16)v.w; lo.w = (f16)((v.w - (float)h.w) * 2048.0f);
        const size_t ro = (size_t)r * U + n0 + c4;
        *(f16x4*)(h0rh + ro) = h;
        *(f16x4*)(h0rl + ro) = lo;
    }
}

// ---------------- main GEMM: g0 = xh-gather @ Gh -- 128x128, 2 blocks/CU --------
__global__ __launch_bounds__(256, 2)
void main5(const f16* __restrict__ xh, const f16* __restrict__ GhT,
           float* __restrict__ g0, f16* __restrict__ g0rh, f16* __restrict__ g0rl)
{
    __shared__ __align__(16) f16 LA[2][8192];    // 16 KB / buf
    __shared__ __align__(16) f16 LB[2][8192];    // 16 KB / buf  (64 KB total)

    const int tid  = threadIdx.x;
    const int lane = tid & 63;
    const int w    = tid >> 6;           // 0..3
    const int wm   = w >> 1;             // 0..1 (row half, 64 rows)
    const int wn   = w & 1;              // 0..1 (col half, 64 cols)
    const int r0   = blockIdx.x * 128;   // 64 row tiles (x => XCD pin)
    const int c0   = blockIdx.y * 128;   // 8 col blocks

    // A staging: 4 chunks/thread; 128 rows x 8 chunks of 16B, swizzled slots
    size_t asrc[4];
    int adst[4];
    #pragma unroll
    for (int i = 0; i < 4; ++i) {
        const int c = tid + 256 * i;        // 0..1023
        const int prow = c >> 3;            // row 0..127
        const int chn = (c & 7) ^ (prow & 7);
        const int arow = r0 + prow;
        const size_t xbase = ((size_t)(arow & 31) * T + (size_t)(arow >> 5) * LJ) * U;
        asrc[i] = xbase * 2 + (size_t)(chn << 4);
        adst[i] = c * 16;
    }
    // B staging: 4 chunks/thread; 128 cols x 8 chunks (col K-line = 16 KB)
    size_t bsrc[4];
    int bdst[4];
    #pragma unroll
    for (int i = 0; i < 4; ++i) {
        const int c = tid + 256 * i;
        const int prow = c >> 3;            // col 0..127
        const int chn = (c & 7) ^ (prow & 7);
        bsrc[i] = ((size_t)(c0 + prow) << 14) + (size_t)(chn << 4);
        bdst[i] = c * 16;
    }

    f32x4 hh[4][4];
    #pragma unroll
    for (int mi = 0; mi < 4; ++mi)
        #pragma unroll
        for (int ni = 0; ni < 4; ++ni)
            hh[mi][ni] = (f32x4){0.f, 0.f, 0.f, 0.f};

    auto stage = [&](int b, int kt) {
        const size_t kb = (size_t)kt << 7;   // 64 f16 = 128 B
        #pragma unroll
        for (int i = 0; i < 4; ++i) {
            gload16((const char*)xh + asrc[i] + kb, (char*)&LA[b][0] + adst[i]);
            gload16((const char*)GhT + bsrc[i] + kb, (char*)&LB[b][0] + bdst[i]);
        }
    };

    stage(0, 0);
    stage(1, 1);    // 16 loads in flight per thread (8 per kt)

    #pragma unroll 1
    for (int kt = 0; kt < 128; ++kt) {
        if (kt < 127) asm volatile("s_waitcnt vmcnt(8)" ::: "memory");
        else          asm volatile("s_waitcnt vmcnt(0)" ::: "memory");
        __builtin_amdgcn_s_barrier();
        asm volatile("" ::: "memory");

        const int buf = kt & 1;
        #pragma unroll
        for (int ks = 0; ks < 2; ++ks) {
            const int kg = ks * 4 + (lane >> 4);
            f16x8 af[4], bh[4];
            #pragma unroll
            for (int mi = 0; mi < 4; ++mi) {
                const int rr = wm * 64 + mi * 16 + (lane & 15);
                const int byte = rr * 128 + ((kg ^ (rr & 7)) << 4);
                af[mi] = *(const f16x8*)((const char*)&LA[buf][0] + byte);
            }
            #pragma unroll
            for (int ni = 0; ni < 4; ++ni) {
                const int cc = wn * 64 + ni * 16 + (lane & 15);
                const int byte = cc * 128 + ((kg ^ (cc & 7)) << 4);
                bh[ni] = *(const f16x8*)((const char*)&LB[buf][0] + byte);
            }
            #pragma unroll
            for (int mi = 0; mi < 4; ++mi)
                #pragma unroll
                for (int ni = 0; ni < 4; ++ni)
                    hh[mi][ni] = __builtin_amdgcn_mfma_f32_16x16x32_f16(af[mi], bh[ni], hh[mi][ni], 0, 0, 0);
        }

        asm volatile("" ::: "memory");
        __builtin_amdgcn_s_barrier();
        asm volatile("" ::: "memory");
        if (kt + 2 < 128) stage(buf, kt + 2);
    }

    #pragma unroll
    for (int mi = 0; mi < 4; ++mi)
        #pragma unroll
        for (int ni = 0; ni < 4; ++ni) {
            const int col = c0 + wn * 64 + ni * 16 + (lane & 15);
            #pragma unroll
            for (int r = 0; r < 4; ++r) {
                const int row = r0 + wm * 64 + mi * 16 + ((lane >> 4) << 2) + r;
                const float val = hh[mi][ni][r];
                const size_t o = (size_t)row * U + col;
                g0[o] = val;
                const f16 hv = (f16)val;
                g0rh[o] = hv;
                g0rl[o] = (f16)((val - (float)hv) * 2048.0f);
            }
        }
}

// ---------------- mk2: all-async split-GEMM, BK=64, counted-vmcnt 2-deep --------
struct MDesc {
    const f16* Ah; const f16* Al;     // row-major [M][1024] pair
    const f16* BhT; const f16* BlT;   // col-major [1024][1024] pair
    const float* Aadd;                // fp32 for amode2 epilogue add
    float* C;                         // fp32 out (or null)
    f16* EhT; f16* ElT;               // transposed emit (or null)
    f16* Rh; f16* Rl;                 // row-split emit (or null)
    long estride, eoff;
    int M;
    int amode;      // 0 linear, 2 tree gather
    int cmode;      // 0 store, 1 add (RMW)
    float cscale, escale, fescale;
};

__global__ __launch_bounds__(256, 1)
void mk2(MDesc d0, MDesc d1)
{
    MDesc d = blockIdx.z ? d1 : d0;
    const int r0 = blockIdx.y * 128;
    if (r0 >= d.M) return;
    const int c0 = blockIdx.x * 64;

    __shared__ __align__(16) f16 SMEM[49152];                // 96 KB
    f16 (*LAs)[2][8192] = (f16(*)[2][8192])(&SMEM[0]);
    f16 (*LBs)[2][4096] = (f16(*)[2][4096])(&SMEM[32768]);

    const int tid = threadIdx.x;
    const int lane = tid & 63;
    const int w = tid >> 6;
    const int wm = w >> 1, wn = w & 1;

    size_t asrc[4]; int adst[4];
    #pragma unroll
    for (int i = 0; i < 4; ++i) {
        const int c = tid + 256 * i;
        const int prow = c >> 3;
        const int chn = (c & 7) ^ (prow & 7);
        int gr = r0 + prow;
        if (gr >= d.M) gr = d.M - 1;
        const int ar = (d.amode == 2) ? (((gr >> 5) << 6) + (gr & 31)) : gr;
        asrc[i] = (size_t)ar * 2048 + (size_t)(chn << 4);
        adst[i] = c * 16;
    }
    size_t bsrc[2]; int bdst[2];
    #pragma unroll
    for (int i = 0; i < 2; ++i) {
        const int c = tid + 256 * i;
        const int prow = c >> 3;
        const int chn = (c & 7) ^ (prow & 7);
        bsrc[i] = (size_t)(c0 + prow) * 2048 + (size_t)(chn << 4);
        bdst[i] = c * 16;
    }

    f32x4 hh[4][2], xx[4][2];
    #pragma unroll
    for (int mi = 0; mi < 4; ++mi)
        #pragma unroll
        for (int ni = 0; ni < 2; ++ni) {
            hh[mi][ni] = (f32x4){0.f, 0.f, 0.f, 0.f};
            xx[mi][ni] = (f32x4){0.f, 0.f, 0.f, 0.f};
        }

    auto stg = [&](int b, int kt) {
        const size_t kb = (size_t)kt << 7;   // 64 f16 = 128 B
        #pragma unroll
        for (int i = 0; i < 4; ++i) {
            gload16((const char*)d.Ah + asrc[i] + kb, (char*)&LAs[b][0][0] + adst[i]);
            gload16((const char*)d.Al + asrc[i] + kb, (char*)&LAs[b][1][0] + adst[i]);
        }
        #pragma unroll
        for (int i = 0; i < 2; ++i) {
            gload16((const char*)d.BhT + bsrc[i] + kb, (char*)&LBs[b][0][0] + bdst[i]);
            gload16((const char*)d.BlT + bsrc[i] + kb, (char*)&LBs[b][1][0] + bdst[i]);
        }
    };

    stg(0, 0);
    stg(1, 1);

    #pragma unroll 1
    for (int kt = 0; kt < 16; ++kt) {
        if (kt < 15) asm volatile("s_waitcnt vmcnt(12)" ::: "memory");
        else         asm volatile("s_waitcnt vmcnt(0)" ::: "memory");
        __builtin_amdgcn_s_barrier();
        asm volatile("" ::: "memory");

        const int buf = kt & 1;
        #pragma unroll
        for (int ks = 0; ks < 2; ++ks) {
            const int kg = ks * 4 + (lane >> 4);
            f16x8 ah[4], al[4], bh[2], bl[2];
            #pragma unroll
            for (int mi = 0; mi < 4; ++mi) {
                const int rr = wm * 64 + mi * 16 + (lane & 15);
                const int byte = rr * 128 + ((kg ^ (rr & 7)) << 4);
                ah[mi] = *(const f16x8*)((const char*)&LAs[buf][0][0] + byte);
                al[mi] = *(const f16x8*)((const char*)&LAs[buf][1][0] + byte);
            }
            #pragma unroll
            for (int ni = 0; ni < 2; ++ni) {
                const int cc = wn * 32 + ni * 16 + (lane & 15);
                const int byte = cc * 128 + ((kg ^ (cc & 7)) << 4);
                bh[ni] = *(const f16x8*)((const char*)&LBs[buf][0][0] + byte);
                bl[ni] = *(const f16x8*)((const char*)&LBs[buf][1][0] + byte);
            }
            #pragma unroll
            for (int mi = 0; mi < 4; ++mi)
                #pragma unroll
                for (int ni = 0; ni < 2; ++ni) {
                    hh[mi][ni] = __builtin_amdgcn_mfma_f32_16x16x32_f16(ah[mi], bh[ni], hh[mi][ni], 0, 0, 0);
                    xx[mi][ni] = __builtin_amdgcn_mfma_f32_16x16x32_f16(ah[mi], bl[ni], xx[mi][ni], 0, 0, 0);
                    xx[mi][ni] = __builtin_amdgcn_mfma_f32_16x16x32_f16(al[mi], bh[ni], xx[mi][ni], 0, 0, 0);
                }
        }

        asm volatile("" ::: "memory");
        __builtin_amdgcn_s_barrier();
        asm volatile("" ::: "memory");
        if (kt + 2 < 16) stg(buf, kt + 2);
    }

    // ---- epilogue ----
    const bool temit = (d.EhT != nullptr);
    f16* Ehs = &SMEM[0];
    f16* Els = &SMEM[8192];

    #pragma unroll
    for (int mi = 0; mi < 4; ++mi) {
        #pragma unroll
        for (int ni = 0; ni < 2; ++ni) {
            const int orow = wm * 64 + mi * 16 + ((lane >> 4) << 2);
            const int colL = wn * 32 + ni * 16 + (lane & 15);
            const int col  = c0 + colL;
            float o[4];
            #pragma unroll
            for (int r = 0; r < 4; ++r) {
                o[r] = (hh[mi][ni][r] + xx[mi][ni][r] * (1.0f / 2048.0f)) * d.cscale;
                const int grow = r0 + orow + r;
                if (grow < d.M) {
                    if (d.amode == 2) {
                        const int arow2 = (((grow >> 5) << 6) + (grow & 31)) + 32;
                        o[r] += d.Aadd[(size_t)arow2 * U + col];
                    }
                    if (d.C) {
                        float* cp = d.C + (size_t)grow * U + col;
                        if (d.cmode == 1) o[r] += *cp;
                        *cp = o[r];
                    }
                    if (d.Rh) {
                        const float e = o[r] * d.fescale;
                        const f16 hv = (f16)e;
                        d.Rh[(size_t)grow * U + col] = hv;
                        d.Rl[(size_t)grow * U + col] = (f16)((e - (float)hv) * 2048.0f);
                    }
                }
            }
            if (temit && (r0 + orow) < d.M) {
                f16x4 h4, l4;
                #pragma unroll
                for (int r = 0; r < 4; ++r) {
                    const float e = o[r] * d.escale;
                    h4[r] = (f16)e;
                    l4[r] = (f16)((e - (float)h4[r]) * 2048.0f);
                }
                const int blk = orow >> 3;
                const int boff = colL * 256 + ((blk ^ (colL & 15)) << 4) + (orow & 7) * 2;
                *(f16x4*)((char*)Ehs + boff) = h4;
                *(f16x4*)((char*)Els + boff) = l4;
            }
        }
    }

    if (temit) {
        __syncthreads();
        const int c  = tid & 63;
        const int b0 = (tid >> 6) * 4;
        const size_t gbase = (size_t)(c0 + c) * d.estride + d.eoff + (size_t)r0;
        #pragma unroll
        for (int i = 0; i < 4; ++i) {
            const int blk = b0 + i;
            const int off = c * 256 + ((blk ^ (c & 15)) << 4);
            *(f16x8*)(d.EhT + gbase + blk * 8) = *(const f16x8*)((char*)Ehs + off);
            *(f16x8*)(d.ElT + gbase + blk * 8) = *(const f16x8*)((char*)Els + off);
        }
    }
}

} // namespace

extern "C" void kernel_launch(void* const* d_in, const int* in_sizes, int n_in,
                              void* d_out, int out_size, void* d_ws, size_t ws_size,
                              hipStream_t stream) {
    const float* x  = (const float*)d_in[0];
    const float* h0 = (const float*)d_in[1];
    const float* W  = (const float*)d_in[2];
    const float* R  = (const float*)d_in[3];
    float* out = (float*)d_out;

    const size_t M1 = (size_t)1024 * 1024;
    float* g0 = (float*)d_ws;            // 8*M1
    float* gA = g0 + 8 * M1;             // 4*M1
    float* gB = gA + 4 * M1;             // 4*M1
    f16* fp = (f16*)(gB + 4 * M1);
    auto take = [&](size_t n) { f16* r = fp; fp += n; return r; };
    f16* xh   = take(64 * M1);
    f16* GhT  = take(8 * M1);
    f16* GlT  = take(8 * M1);
    f16* Tqh[8]; f16* Tql[8];
    for (int l = 0; l < 8; ++l) { Tqh[l] = take(M1); Tql[l] = take(M1); }
    f16* Qrh[7]; f16* Qrl[7];
    for (int l = 0; l < 7; ++l) { Qrh[l] = take(M1); Qrl[l] = take(M1); }
    f16* Gfrh = take(4 * M1); f16* Gfrl = take(4 * M1);
    f16* h0rh = take(32 * 1024); f16* h0rl = take(32 * 1024);
    f16* g0rh = take(8 * M1); f16* g0rl = take(8 * M1);
    f16* gArh = take(4 * M1); f16* gArl = take(4 * M1);
    f16* gBrh = take(4 * M1); f16* gBrl = take(4 * M1);
    // aliases (time-disjoint, R13-verified):
    f16* TTRh = Tqh[3]; f16* TTRl = Tql[3];
    f16* TT1h = Tqh[1]; f16* TT1l = Tql[1];
    f16* TT2h = Tqh[2]; f16* TT2l = Tql[2];
    f16* Rrh  = Qrh[3]; f16* Rrl  = Qrl[3];
    f16* R2rh = Qrh[1]; f16* R2rl = Qrl[1];
    f16* R4rh = Qrh[2]; f16* R4rl = Qrl[2];

    auto MD2 = [](const f16* Ah, const f16* Al, const f16* Bh, const f16* Bl,
                  const float* Aadd, float* C, f16* Eh, f16* El, long eoff, long estride,
                  f16* Rh, f16* Rl, int M, int amode, int cmode,
                  float cs, float es, float fs) {
        MDesc d;
        d.Ah = Ah; d.Al = Al; d.BhT = Bh; d.BlT = Bl; d.Aadd = Aadd; d.C = C;
        d.EhT = Eh; d.ElT = El; d.Rh = Rh; d.Rl = Rl;
        d.estride = estride; d.eoff = eoff; d.M = M; d.amode = amode; d.cmode = cmode;
        d.cscale = cs; d.escale = es; d.fescale = fs;
        return d;
    };
    MDesc dz = MD2(nullptr, nullptr, nullptr, nullptr, nullptr, nullptr,
                   nullptr, nullptr, 0, 1024, nullptr, nullptr, 0, 0, 0, 1.f, 1.f, 1.f);
    auto PAIR = [&](MDesc a, MDesc b) {
        int y0 = (a.M + 127) >> 7, y1 = (b.M + 127) >> 7;
        int y = y0 > y1 ? y0 : y1; if (y < 1) y = 1;
        mk2<<<dim3(16, (unsigned)y, 2), 256, 0, stream>>>(a, b);
    };

    // 0) conversions
    prep<<<dim3(32, 32, 2), 256, 0, stream>>>(R, W, h0, TTRh, TTRl, Rrh, Rrl,
                                              GhT, GlT,
                                              Gfrh + 3 * M1, Gfrl + 3 * M1,
                                              h0rh, h0rl);
    split_x<<<2048, 256, 0, stream>>>(x, xh, (long)BATCH * T * U / 4);

    // 1) G-build + R-power chain, 3 fused launches
    PAIR(MD2(Rrh, Rrl, TTRh, TTRl, nullptr, nullptr, TT1h, TT1l, 0, 1024,
             R2rh, R2rl, U, 0, 0, 1.f, 1.f, 1.f),                               // R^2
         MD2(Gfrh + 3 * M1, Gfrl + 3 * M1, TTRh, TTRl, nullptr, nullptr,
             GhT, GlT, 6144, 8192, Gfrh + 2 * M1, Gfrl + 2 * M1, U, 0, 0, 1.f, 1.f, 1.f)); // WR -> seg6
    PAIR(MD2(R2rh, R2rl, TT1h, TT1l, nullptr, nullptr, TT2h, TT2l, 0, 1024,
             R4rh, R4rl, U, 0, 0, 1.f, 1.f, 1.f),                               // R^4
         MD2(Gfrh + 2 * M1, Gfrl + 2 * M1, TT1h, TT1l, nullptr, nullptr,
             GhT, GlT, 4096, 8192, Gfrh, Gfrl, 2 * U, 0, 0, 1.f, 1.f, 1.f));    // segs 4,5
    PAIR(MD2(R4rh, R4rl, TT2h, TT2l, nullptr, nullptr, Tqh[0], Tql[0], 0, 1024,
             Qrh[0], Qrl[0], U, 0, 0, 1.f, 1.f, 1.f),                           // R^8
         MD2(Gfrh, Gfrl, TT2h, TT2l, nullptr, nullptr,
             GhT, GlT, 0, 8192, nullptr, nullptr, 4 * U, 0, 0, 1.f, 1.f, 1.f)); // segs 0..3

    // 2) main GEMM (hi-only B; emits g0 row-split); grid (row, col) for XCD pin
    main5<<<dim3(64, 8), 256, 0, stream>>>(xh, GhT, g0, g0rh, g0rl);

    // 3) inject (g0[0:32] += h0 @ R^8, RMW + re-emit) || squaring0
    PAIR(MD2(h0rh, h0rl, Tqh[0], Tql[0], nullptr, g0, nullptr, nullptr, 0, 1024,
             g0rh, g0rl, BATCH, 0, 1, 1.f, 1.f, 1.f),
         MD2(Qrh[0], Qrl[0], Tqh[0], Tql[0], nullptr, nullptr, Tqh[1], Tql[1], 0, 1024,
             Qrh[1], Qrl[1], U, 0, 0, 1.f, 1.f, 1.f));

    // 4) tree: 8 levels; combine l || squaring l+1
    const float aS[9] = {1.f, 1.f, 1.f, 1.f, 1.f,
                         0.015625f, 9.5367431640625e-07f, 7.105427357601002e-15f, 0.f};
    const float cS[8] = {1.f, 1.f, 1.f, 1.f, 1.f,
                         64.f, 68719476736.f, 1.5474250491067253e26f};
    float* gcur = g0; f16* gcrh = g0rh; f16* gcrl = g0rl;
    float* gnxt = gA; f16* gnrh = gArh; f16* gnrl = gArl;
    float* gprv = gB; f16* gprh = gBrh; f16* gprl = gBrl;
    for (int l = 0; l < 8; ++l) {
        const int M = BATCH * ((CJ / 2) >> l);    // 4096 ... 32
        MDesc dc = MD2(gcrh, gcrl, Tqh[l], Tql[l], gcur, (l == 7) ? out : gnxt,
                       nullptr, nullptr, 0, 1024,
                       (l < 7) ? gnrh : nullptr, (l < 7) ? gnrl : nullptr,
                       M, 2, 0, cS[l], 1.f, aS[l + 1]);
        MDesc dq = dz;
        if (l < 6) {
            const int s = l + 1;
            const float fe = (s == 5) ? 5.960464477539063e-08f : 1.f;   // 2^-24
            const float te = (s == 5) ? 1.52587890625e-05f : 1.f;       // 2^-16
            f16* reh = (s + 1 <= 6) ? Qrh[s + 1] : nullptr;
            f16* rel = (s + 1 <= 6) ? Qrl[s + 1] : nullptr;
            dq = MD2(Qrh[s], Qrl[s], Tqh[s], Tql[s], nullptr, nullptr,
                     Tqh[s + 1], Tql[s + 1], 0, 1024, reh, rel, U, 0, 0, 1.f, te, fe);
        }
        PAIR(dc, dq);
        float* tf = gprv; gprv = gcur; gcur = gnxt; gnxt = tf;
        f16* th = gprh; f16* tl = gprl;
        gprh = gcrh; gprl = gcrl;
        gcrh = gnrh; gcrl = gnrl;
        gnrh = th;   gnrl = tl;
    }
    (void)in_sizes; (void)n_in; (void)out_size; (void)ws_size;
}